// Round 1
// baseline (448.397 us; speedup 1.0000x reference)
//
#include <hip/hip_runtime.h>

#define PI_F 3.14159265358979f

// ---------------------------------------------------------------------------
// In-LDS radix-2 DIT complex FFT, one wave (64 lanes) per transform.
// s points to this wave's private LDS region of N float2.
// All waves in the block execute the same uniform barrier sequence.
// ---------------------------------------------------------------------------
template<int LOGN, bool INV>
__device__ __forceinline__ void wave_fft(float2* s, int lane) {
    constexpr int N  = 1 << LOGN;
    constexpr int R  = (N + 63) / 64;       // elements per lane
    constexpr int BT = (N / 2 + 63) / 64;   // butterflies per lane per stage

    // bit-reversal permute (read all into regs, barrier, write back)
    float2 tmp[R];
#pragma unroll
    for (int t = 0; t < R; ++t) {
        int i = lane + t * 64;
        int r = __brev((unsigned)i) >> (32 - LOGN);
        tmp[t] = s[r];
    }
    __syncthreads();
#pragma unroll
    for (int t = 0; t < R; ++t) {
        int i = lane + t * 64;
        s[i] = tmp[t];
    }
    __syncthreads();

#pragma unroll
    for (int stage = 1; stage <= LOGN; ++stage) {
        const int half = 1 << (stage - 1);
#pragma unroll
        for (int t = 0; t < BT; ++t) {
            int b = lane + t * 64;
            if (b < N / 2) {
                int pos = b & (half - 1);
                int i0  = ((b >> (stage - 1)) << stage) + pos;
                int i1  = i0 + half;
                float ang = (INV ? 2.0f * PI_F : -2.0f * PI_F) * (float)pos / (float)(2 * half);
                float sn, cs;
                __sincosf(ang, &sn, &cs);
                float2 a0 = s[i0], a1 = s[i1];
                float2 w  = make_float2(a1.x * cs - a1.y * sn, a1.x * sn + a1.y * cs);
                s[i0] = make_float2(a0.x + w.x, a0.y + w.y);
                s[i1] = make_float2(a0.x - w.x, a0.y - w.y);
            }
        }
        __syncthreads();
    }
}

// ---------------------------------------------------------------------------
// D4 symmetrization of kernel: out[i][j] = mean of 8 dihedral transforms.
// 512 images of 128x128.
// ---------------------------------------------------------------------------
__global__ void sym_k(const float* __restrict__ kin, float* __restrict__ kout) {
    int idx = blockIdx.x * 256 + threadIdx.x;     // 512*128*128 total
    int j   = idx & 127;
    int i   = (idx >> 7) & 127;
    int img = idx >> 14;
    const float* p = kin + (size_t)img * 16384;
    int ni = (128 - i) & 127, nj = (128 - j) & 127;
    float v = p[i * 128 + j]  + p[nj * 128 + i]  + p[ni * 128 + nj] + p[j * 128 + ni]
            + p[j * 128 + i]  + p[i * 128 + nj]  + p[ni * 128 + j]  + p[nj * 128 + ni];
    kout[idx] = v * 0.125f;
}

// ---------------------------------------------------------------------------
// Row-wise real FFT of length N (N = 128 or 256) via complex FFT of N/2.
// Stores X[k], k = 0..64 (65 complex per row). One wave per row, 4 waves/block.
// ---------------------------------------------------------------------------
template<int LOGN>   // 7 => N=128 (kernel), 8 => N=256 (f)
__global__ void rfft_rows(const float* __restrict__ in, float2* __restrict__ out) {
    constexpr int N = 1 << LOGN;
    constexpr int M = N / 2;
    __shared__ float2 sm[4][M];
    int wave = threadIdx.x >> 6, lane = threadIdx.x & 63;
    int row  = blockIdx.x * 4 + wave;
    float2* s = sm[wave];
    const float2* x = (const float2*)(in + (size_t)row * N);   // packed pairs
#pragma unroll
    for (int t = 0; t < M / 64; ++t) {
        int n = lane + t * 64;
        s[n] = x[n];       // z[n] = x[2n] + i x[2n+1]
    }
    __syncthreads();
    wave_fft<LOGN - 1, false>(s, lane);
    // unpack to X[k], k=0..64
    float2* o = out + (size_t)row * 65;
    for (int k = lane; k <= 64; k += 64) {
        float2 zk = s[k & (M - 1)];
        float2 zm = s[(M - k) & (M - 1)];
        float ar = zk.x + zm.x, ai = zk.y - zm.y;   // A = Z[k] + conj(Z[M-k])
        float br = zk.x - zm.x, bi = zk.y + zm.y;   // B = Z[k] - conj(Z[M-k])
        float ang = -PI_F * (float)k / (float)M;    // = -2*pi*k/N
        float sn, cs;
        __sincosf(ang, &sn, &cs);
        float p = cs * br - sn * bi;                // w*B
        float q = cs * bi + sn * br;
        o[k] = make_float2(0.5f * (ar + q), 0.5f * (ai - p));   // 0.5*(A - i*w*B)
    }
}

// ---------------------------------------------------------------------------
// Column-wise complex FFT length 128 over 65-column complex arrays, in place.
// fid = img*65 + k2. INV adds +sign twiddles; scale applied at store.
// ---------------------------------------------------------------------------
template<bool INV>
__global__ void fft_cols128(float2* __restrict__ buf, float scale) {
    __shared__ float2 sm[4][128];
    int wave = threadIdx.x >> 6, lane = threadIdx.x & 63;
    int fid  = blockIdx.x * 4 + wave;
    int img  = fid / 65, k2 = fid % 65;
    float2* base = buf + (size_t)img * 128 * 65 + k2;
    float2* s = sm[wave];
#pragma unroll
    for (int t = 0; t < 2; ++t) { int r = lane + t * 64; s[r] = base[(size_t)r * 65]; }
    __syncthreads();
    wave_fft<7, INV>(s, lane);
#pragma unroll
    for (int t = 0; t < 2; ++t) {
        int r = lane + t * 64;
        float2 v = s[r];
        base[(size_t)r * 65] = make_float2(v.x * scale, v.y * scale);
    }
}

// ---------------------------------------------------------------------------
// Column-wise complex FFT length 256 on f's row-spectrum, truncated to the
// 128-row signed-frequency set {0..63, [64]=0, -63..-1}, Nyquist col zeroed,
// scaled by (N2/N1)^2 = 0.25.  g: (128,256,65) -> fhat: (128,128,65)
// ---------------------------------------------------------------------------
__global__ void fft_cols256_trunc(const float2* __restrict__ g, float2* __restrict__ fhat) {
    __shared__ float2 sm[4][256];
    int wave = threadIdx.x >> 6, lane = threadIdx.x & 63;
    int fid  = blockIdx.x * 4 + wave;       // 128*65 total
    int img  = fid / 65, k2 = fid % 65;
    const float2* src = g + (size_t)img * 256 * 65 + k2;
    float2* s = sm[wave];
#pragma unroll
    for (int t = 0; t < 4; ++t) { int r = lane + t * 64; s[r] = src[(size_t)r * 65]; }
    __syncthreads();
    wave_fft<8, false>(s, lane);
    float2* dst = fhat + (size_t)img * 128 * 65 + k2;
#pragma unroll
    for (int t = 0; t < 2; ++t) {
        int orow = lane + t * 64;
        int srow = orow < 64 ? orow : orow + 128;   // 65..127 -> 193..255 (k=-63..-1)
        float2 v = s[srow];
        if (orow == 64 || k2 == 64) v = make_float2(0.f, 0.f);   // Nyquist zeroing
        dst[(size_t)orow * 65] = make_float2(v.x * 0.25f, v.y * 0.25f);
    }
}

// ---------------------------------------------------------------------------
// Per-frequency complex contraction: C[b,d] = sum_c F[b,c] * K[c,d]
// One block per (n,k) frequency; 256 threads = one (b,d) each.
// ---------------------------------------------------------------------------
__global__ void einsum_k(const float2* __restrict__ F, const float2* __restrict__ K,
                         float2* __restrict__ C) {
    __shared__ float2 Fs[128];
    __shared__ float2 Ks[512];
    int nk = blockIdx.x;                    // n*65 + k, 8320 total
    int t  = threadIdx.x;
    if (t < 128) Fs[t] = F[(size_t)t * 8320 + nk];
    Ks[t]       = K[(size_t)t * 8320 + nk];
    Ks[t + 256] = K[(size_t)(t + 256) * 8320 + nk];
    __syncthreads();
    int b = t >> 5, d = t & 31;
    float2 acc = make_float2(0.f, 0.f);
#pragma unroll
    for (int c = 0; c < 16; ++c) {
        float2 a = Fs[b * 16 + c];
        float2 w = Ks[c * 32 + d];
        acc.x += a.x * w.x - a.y * w.y;
        acc.y += a.x * w.y + a.y * w.x;
    }
    C[(size_t)(b * 32 + d) * 8320 + nk] = acc;
}

// ---------------------------------------------------------------------------
// Row-wise inverse real FFT, N=128 output reals from X[0..64], via icfft64.
// Includes the 1/64 normalization of this axis (column kernel applied 1/128).
// ---------------------------------------------------------------------------
__global__ void irfft_rows(const float2* __restrict__ in, float* __restrict__ out) {
    constexpr int M = 64;
    __shared__ float2 sm[4][M];
    __shared__ float2 xs[4][65];
    int wave = threadIdx.x >> 6, lane = threadIdx.x & 63;
    int row  = blockIdx.x * 4 + wave;
    const float2* xr = in + (size_t)row * 65;
    for (int k = lane; k <= 64; k += 64) xs[wave][k] = xr[k];
    __syncthreads();
    {
        int k = lane;                        // 0..63
        float2 Xk = xs[wave][k];
        float2 Xm = xs[wave][64 - k];
        float er = 0.5f * (Xk.x + Xm.x), ei = 0.5f * (Xk.y - Xm.y);   // E
        float br = 0.5f * (Xk.x - Xm.x), bi = 0.5f * (Xk.y + Xm.y);   // B
        float ang = PI_F * (float)k / (float)M;                        // +2*pi*k/128
        float sn, cs;
        __sincosf(ang, &sn, &cs);
        float orr = cs * br - sn * bi;       // O = w*B
        float oi  = cs * bi + sn * br;
        sm[wave][k] = make_float2(er - oi, ei + orr);   // Z = E + i*O
    }
    __syncthreads();
    wave_fft<6, true>(sm[wave], lane);
    float2* o = (float2*)(out + (size_t)row * 128);
    {
        int n = lane;
        float2 z = sm[wave][n];
        o[n] = make_float2(z.x * (1.0f / 64.0f), z.y * (1.0f / 64.0f));
    }
}

// ---------------------------------------------------------------------------
// Launch
// ---------------------------------------------------------------------------
extern "C" void kernel_launch(void* const* d_in, const int* in_sizes, int n_in,
                              void* d_out, int out_size, void* d_ws, size_t ws_size,
                              hipStream_t stream) {
    const float* f   = (const float*)d_in[0];   // (8,16,256,256)
    const float* kin = (const float*)d_in[1];   // (1,16,32,128,128)
    float* out = (float*)d_out;                 // out0 (8,16,128,128) | out1 (8,32,128,128)
    char* ws = (char*)d_ws;

    // workspace layout (bytes):
    //   [0, 33554432)              : SYM (512*128*128 f32)         -- later reused:
    //       [0, 17039360)          : G    (128,256,65) c64   then CONV (256,128,65) c64
    //       [17039360, 25559040)   : FHAT (128,128,65) c64
    //   [33554432, 67633152)       : KB   (512,128,65) c64
    float*  SYM  = (float*)ws;
    float2* G    = (float2*)ws;
    float2* CONV = (float2*)ws;
    float2* FHAT = (float2*)(ws + 17039360);
    float2* KB   = (float2*)(ws + 33554432);

    // kernel path: symmetrize -> row rfft(128) -> col fft(128)
    sym_k<<<32768, 256, 0, stream>>>(kin, SYM);
    rfft_rows<7><<<16384, 256, 0, stream>>>(SYM, KB);          // 512*128 rows
    fft_cols128<false><<<8320, 256, 0, stream>>>(KB, 1.0f);    // 512*65 cols

    // f path: row rfft(256) -> col fft(256) truncated+scaled
    rfft_rows<8><<<8192, 256, 0, stream>>>(f, G);              // 128*256 rows
    fft_cols256_trunc<<<2080, 256, 0, stream>>>(G, FHAT);      // 128*65 cols

    // per-frequency contraction
    einsum_k<<<8320, 256, 0, stream>>>(FHAT, KB, CONV);

    // inverse transforms (col ifft includes 1/128, row irfft includes 1/64)
    fft_cols128<true><<<2080, 256, 0, stream>>>(FHAT, 1.0f / 128.0f);   // 128*65
    fft_cols128<true><<<4160, 256, 0, stream>>>(CONV, 1.0f / 128.0f);   // 256*65
    irfft_rows<<<4096, 256, 0, stream>>>(FHAT, out);                    // 128*128 rows
    irfft_rows<<<8192, 256, 0, stream>>>(CONV, out + 2097152);          // 256*128 rows
}

// Round 2
// 276.674 us; speedup vs baseline: 1.6207x; 1.6207x over previous
//
#include <hip/hip_runtime.h>

#define PI_F 3.14159265358979f

// ---------------------------------------------------------------------------
// In-LDS radix-2 DIT complex FFT, one wave (64 lanes) per transform.
// ---------------------------------------------------------------------------
template<int LOGN, bool INV>
__device__ __forceinline__ void wave_fft(float2* s, int lane) {
    constexpr int N  = 1 << LOGN;
    constexpr int R  = (N + 63) / 64;
    constexpr int BT = (N / 2 + 63) / 64;

    float2 tmp[R];
#pragma unroll
    for (int t = 0; t < R; ++t) {
        int i = lane + t * 64;
        int r = __brev((unsigned)i) >> (32 - LOGN);
        tmp[t] = s[r];
    }
    __syncthreads();
#pragma unroll
    for (int t = 0; t < R; ++t) s[lane + t * 64] = tmp[t];
    __syncthreads();

#pragma unroll
    for (int stage = 1; stage <= LOGN; ++stage) {
        const int half = 1 << (stage - 1);
#pragma unroll
        for (int t = 0; t < BT; ++t) {
            int b = lane + t * 64;
            if (b < N / 2) {
                int pos = b & (half - 1);
                int i0  = ((b >> (stage - 1)) << stage) + pos;
                int i1  = i0 + half;
                float ang = (INV ? 2.0f * PI_F : -2.0f * PI_F) * (float)pos / (float)(2 * half);
                float sn, cs;
                __sincosf(ang, &sn, &cs);
                float2 a0 = s[i0], a1 = s[i1];
                float2 w  = make_float2(a1.x * cs - a1.y * sn, a1.x * sn + a1.y * cs);
                s[i0] = make_float2(a0.x + w.x, a0.y + w.y);
                s[i1] = make_float2(a0.x - w.x, a0.y - w.y);
            }
        }
        __syncthreads();
    }
}

// ---------------------------------------------------------------------------
// D4 symmetrization, block-per-image via LDS (XOR-swizzled to avoid bank
// conflicts on transposed reads). 512 images of 128x128.
// ---------------------------------------------------------------------------
__device__ __forceinline__ int sw(int i, int j) { return i * 128 + (j ^ (i & 31)); }

__global__ void sym_k_lds(const float* __restrict__ kin, float* __restrict__ kout) {
    __shared__ float s[16384];                 // 64 KB
    int img = blockIdx.x, t = threadIdx.x;
    const float4* in4 = (const float4*)(kin + (size_t)img * 16384);
    float4* out4      = (float4*)(kout + (size_t)img * 16384);
#pragma unroll
    for (int k = 0; k < 16; ++k) {
        int idx4 = t + k * 256;                // 4096 float4
        int i = idx4 >> 5, j0 = (idx4 & 31) * 4;
        float4 v = in4[idx4];
        s[sw(i, j0 + 0)] = v.x; s[sw(i, j0 + 1)] = v.y;
        s[sw(i, j0 + 2)] = v.z; s[sw(i, j0 + 3)] = v.w;
    }
    __syncthreads();
#pragma unroll
    for (int k = 0; k < 16; ++k) {
        int idx4 = t + k * 256;
        int i = idx4 >> 5, j0 = (idx4 & 31) * 4;
        float4 o;
        float* op = (float*)&o;
#pragma unroll
        for (int m = 0; m < 4; ++m) {
            int j = j0 + m;
            int ni = (128 - i) & 127, nj = (128 - j) & 127;
            float v = s[sw(i, j)]  + s[sw(nj, i)]  + s[sw(ni, nj)] + s[sw(j, ni)]
                    + s[sw(j, i)]  + s[sw(i, nj)]  + s[sw(ni, j)]  + s[sw(nj, ni)];
            op[m] = v * 0.125f;
        }
        out4[idx4] = o;
    }
}

// ---------------------------------------------------------------------------
// Row-wise real FFT length N via cfft(N/2). Stores k = 0..63 only (64 cols;
// the Nyquist col 64 is masked to zero downstream and never needed).
// One wave per row, 4 waves/block.
// ---------------------------------------------------------------------------
template<int LOGN>   // 7 => N=128 (kernel), 8 => N=256 (f)
__global__ void rfft_rows(const float* __restrict__ in, float2* __restrict__ out) {
    constexpr int N = 1 << LOGN;
    constexpr int M = N / 2;
    __shared__ float2 sm[4][M];
    int wave = threadIdx.x >> 6, lane = threadIdx.x & 63;
    int row  = blockIdx.x * 4 + wave;
    float2* s = sm[wave];
    const float2* x = (const float2*)(in + (size_t)row * N);
#pragma unroll
    for (int t = 0; t < M / 64; ++t) { int n = lane + t * 64; s[n] = x[n]; }
    __syncthreads();
    wave_fft<LOGN - 1, false>(s, lane);
    float2* o = out + (size_t)row * 64;
    int k = lane;                               // 0..63
    float2 zk = s[k];
    float2 zm = s[(M - k) & (M - 1)];
    float ar = zk.x + zm.x, ai = zk.y - zm.y;
    float br = zk.x - zm.x, bi = zk.y + zm.y;
    float ang = -PI_F * (float)k / (float)M;
    float sn, cs;
    __sincosf(ang, &sn, &cs);
    float p = cs * br - sn * bi;
    float q = cs * bi + sn * br;
    o[k] = make_float2(0.5f * (ar + q), 0.5f * (ai - p));
}

// ---------------------------------------------------------------------------
// Batched in-LDS column FFT: R rows x C cols of float2 in LDS, 256 threads.
// Input must be loaded in bit-reversed row order.
// ---------------------------------------------------------------------------
template<int LOGR, int LOGC, bool INV>
__device__ __forceinline__ void block_fft_cols(float2* s) {
    constexpr int C = 1 << LOGC;
    constexpr int TOT = (1 << (LOGR - 1)) * C;   // butterflies per stage
#pragma unroll
    for (int stage = 1; stage <= LOGR; ++stage) {
        int half = 1 << (stage - 1);
        for (int idx = threadIdx.x; idx < TOT; idx += 256) {
            int col = idx & (C - 1);
            int b   = idx >> LOGC;
            int pos = b & (half - 1);
            int i0  = ((b >> (stage - 1)) << stage) + pos;
            int i1  = i0 + half;
            float ang = (INV ? 2.0f * PI_F : -2.0f * PI_F) * (float)pos / (float)(2 * half);
            float sn, cs;
            __sincosf(ang, &sn, &cs);
            float2 a0 = s[i0 * C + col], a1 = s[i1 * C + col];
            float2 w  = make_float2(a1.x * cs - a1.y * sn, a1.x * sn + a1.y * cs);
            s[i0 * C + col] = make_float2(a0.x + w.x, a0.y + w.y);
            s[i1 * C + col] = make_float2(a0.x - w.x, a0.y - w.y);
        }
        __syncthreads();
    }
}

// 128-point forward column FFT, in place on (img, 128, 64) complex.
__global__ void fft_col_kb(float2* __restrict__ buf) {
    __shared__ float2 s[8192];                  // 64 KB
    float2* base = buf + (size_t)blockIdx.x * 8192;
    for (int idx = threadIdx.x; idx < 8192; idx += 256) {
        int row = idx >> 6, col = idx & 63;
        int br  = __brev((unsigned)row) >> 25;
        s[br * 64 + col] = base[idx];
    }
    __syncthreads();
    block_fft_cols<7, 6, false>(s);
    for (int idx = threadIdx.x; idx < 8192; idx += 256) base[idx] = s[idx];
}

// 128-point inverse column FFT, in place, with scale.
__global__ void fft_col_inv(float2* __restrict__ buf, float scale) {
    __shared__ float2 s[8192];
    float2* base = buf + (size_t)blockIdx.x * 8192;
    for (int idx = threadIdx.x; idx < 8192; idx += 256) {
        int row = idx >> 6, col = idx & 63;
        int br  = __brev((unsigned)row) >> 25;
        s[br * 64 + col] = base[idx];
    }
    __syncthreads();
    block_fft_cols<7, 6, true>(s);
    for (int idx = threadIdx.x; idx < 8192; idx += 256) {
        float2 v = s[idx];
        base[idx] = make_float2(v.x * scale, v.y * scale);
    }
}

// 256-point forward column FFT on G (img, 256, 64), truncated to the signed
// 128-row set {0..63, [64]=0, -63..-1}, scaled 0.25, into FHAT (img, 128, 64).
// One block per (img, 32-col half).
__global__ void fft_col256t(const float2* __restrict__ g, float2* __restrict__ fh) {
    __shared__ float2 s[8192];                  // 256 x 32
    int img = blockIdx.x >> 1, h = blockIdx.x & 1;
    const float2* src = g + (size_t)img * 16384 + h * 32;
    for (int idx = threadIdx.x; idx < 8192; idx += 256) {
        int row = idx >> 5, col = idx & 31;
        int br  = __brev((unsigned)row) >> 24;
        s[br * 32 + col] = src[(size_t)row * 64 + col];
    }
    __syncthreads();
    block_fft_cols<8, 5, false>(s);
    float2* dst = fh + (size_t)img * 8192 + h * 32;
    for (int idx = threadIdx.x; idx < 4096; idx += 256) {
        int orow = idx >> 5, col = idx & 31;
        int srow = orow < 64 ? orow : orow + 128;   // 65..127 -> k=-63..-1
        float2 v = s[srow * 32 + col];
        if (orow == 64) v = make_float2(0.f, 0.f);
        dst[(size_t)orow * 64 + col] = make_float2(v.x * 0.25f, v.y * 0.25f);
    }
}

// ---------------------------------------------------------------------------
// Per-frequency contraction C[b,d,nk] = sum_c F[b,c,nk]*K[c,d,nk], nk=n*64+k.
// 64 lanes = 64 consecutive nk (coalesced); F held in registers per b.
// Grid 1024: {nk-group 128} x {b-half 2} x {d-quarter 4}.
// ---------------------------------------------------------------------------
__global__ void einsum_k2(const float2* __restrict__ F, const float2* __restrict__ K,
                          float2* __restrict__ C) {
    int bid = blockIdx.x;
    int nkg = bid & 127;
    int bh  = (bid >> 7) & 1;
    int dq  = bid >> 8;
    int lane = threadIdx.x & 63, wave = threadIdx.x >> 6;
    int b  = bh * 4 + wave;
    int nk = nkg * 64 + lane;
    float2 Freg[16];
#pragma unroll
    for (int c = 0; c < 16; ++c) Freg[c] = F[(size_t)(b * 16 + c) * 8192 + nk];
#pragma unroll
    for (int dd = 0; dd < 8; ++dd) {
        int d = dq * 8 + dd;
        float2 acc = make_float2(0.f, 0.f);
#pragma unroll
        for (int c = 0; c < 16; ++c) {
            float2 a = Freg[c];
            float2 w = K[(size_t)(c * 32 + d) * 8192 + nk];
            acc.x += a.x * w.x - a.y * w.y;
            acc.y += a.x * w.y + a.y * w.x;
        }
        C[(size_t)(b * 32 + d) * 8192 + nk] = acc;
    }
}

// ---------------------------------------------------------------------------
// Row-wise inverse real FFT: 128 reals from X[0..63] (X[64] == 0), via
// icfft64. Includes 1/64 (column pass applied 1/128).
// ---------------------------------------------------------------------------
__global__ void irfft_rows(const float2* __restrict__ in, float* __restrict__ out) {
    constexpr int M = 64;
    __shared__ float2 sm[4][M];
    int wave = threadIdx.x >> 6, lane = threadIdx.x & 63;
    int row  = blockIdx.x * 4 + wave;
    const float2* xr = in + (size_t)row * 64;
    float2 Xk = xr[lane];
    float2 Xm = (lane == 0) ? make_float2(0.f, 0.f) : xr[64 - lane];
    float er = 0.5f * (Xk.x + Xm.x), ei = 0.5f * (Xk.y - Xm.y);
    float br = 0.5f * (Xk.x - Xm.x), bi = 0.5f * (Xk.y + Xm.y);
    float ang = PI_F * (float)lane / (float)M;
    float sn, cs;
    __sincosf(ang, &sn, &cs);
    float orr = cs * br - sn * bi;
    float oi  = cs * bi + sn * br;
    sm[wave][lane] = make_float2(er - oi, ei + orr);
    __syncthreads();
    wave_fft<6, true>(sm[wave], lane);
    float2* o = (float2*)(out + (size_t)row * 128);
    float2 z = sm[wave][lane];
    o[lane] = make_float2(z.x * (1.0f / 64.0f), z.y * (1.0f / 64.0f));
}

// ---------------------------------------------------------------------------
// Launch
// ---------------------------------------------------------------------------
extern "C" void kernel_launch(void* const* d_in, const int* in_sizes, int n_in,
                              void* d_out, int out_size, void* d_ws, size_t ws_size,
                              hipStream_t stream) {
    const float* f   = (const float*)d_in[0];   // (8,16,256,256)
    const float* kin = (const float*)d_in[1];   // (1,16,32,128,128)
    float* out = (float*)d_out;                 // out0 (8,16,128,128) | out1 (8,32,128,128)
    char* ws = (char*)d_ws;

    // workspace (bytes), with lifetime-based reuse:
    //   [0, 33554432)  : SYM (512*16384 f32)  -> then G (128,256,64 c64, 16 MB)
    //                    -> then CONV (256,128,64 c64, 16 MB)
    //   [16777216, 25165824) : FHAT (128,128,64 c64, 8 MB)  (after SYM dead)
    //   [33554432, 67108864) : KB (512,128,64 c64, 32 MB)
    float*  SYM  = (float*)ws;
    float2* G    = (float2*)ws;
    float2* CONV = (float2*)ws;
    float2* FHAT = (float2*)(ws + 16777216);
    float2* KB   = (float2*)(ws + 33554432);

    // kernel path
    sym_k_lds<<<512, 256, 0, stream>>>(kin, SYM);
    rfft_rows<7><<<16384, 256, 0, stream>>>(SYM, KB);      // 512*128 rows
    fft_col_kb<<<512, 256, 0, stream>>>(KB);

    // f path
    rfft_rows<8><<<8192, 256, 0, stream>>>(f, G);          // 128*256 rows
    fft_col256t<<<256, 256, 0, stream>>>(G, FHAT);

    // contraction
    einsum_k2<<<1024, 256, 0, stream>>>(FHAT, KB, CONV);

    // inverse transforms
    fft_col_inv<<<128, 256, 0, stream>>>(FHAT, 1.0f / 128.0f);
    fft_col_inv<<<256, 256, 0, stream>>>(CONV, 1.0f / 128.0f);
    irfft_rows<<<4096, 256, 0, stream>>>(FHAT, out);               // 8*16*128 rows
    irfft_rows<<<8192, 256, 0, stream>>>(CONV, out + 2097152);     // 8*32*128 rows
}

// Round 3
// 212.661 us; speedup vs baseline: 2.1085x; 1.3010x over previous
//
#include <hip/hip_runtime.h>

#define PI_F 3.14159265358979f

// tw[j] = exp(-i*pi*j/128). Twiddle for a radix-2 stage with half-size h:
// W = exp(-i*pi*pos/h) = tw[pos * (128/h)] = tw[pos << (8 - stage)].
__device__ __forceinline__ void tw_init(float2* tw) {
    if (threadIdx.x < 128) {
        float sn, cs;
        __sincosf(-PI_F * (float)threadIdx.x * (1.0f / 128.0f), &sn, &cs);
        tw[threadIdx.x] = make_float2(cs, sn);
    }
}

__device__ __forceinline__ void bfly(float2& a0, float2& a1, float cs, float sn) {
    float tr = a1.x * cs - a1.y * sn;
    float ti = a1.x * sn + a1.y * cs;
    a1.x = a0.x - tr; a1.y = a0.y - ti;
    a0.x += tr;       a0.y += ti;
}

// Batched FFT along the contiguous (inner) axis: nbatch rows of length N,
// row-major, input pre-bit-reversed. Block-wide, NT threads.
template<int LOGN, bool INV, int NT>
__device__ __forceinline__ void fft_inner(float2* s, int nbatch, const float2* tw) {
    constexpr int N = 1 << LOGN;
#pragma unroll
    for (int stage = 1; stage <= LOGN; ++stage) {
        const int h = 1 << (stage - 1);
        const int total = (N / 2) * nbatch;
        for (int idx = threadIdx.x; idx < total; idx += NT) {
            int q = idx & (N / 2 - 1);
            int b = idx >> (LOGN - 1);
            int pos = q & (h - 1);
            int i0 = b * N + ((q >> (stage - 1)) << stage) + pos;
            int i1 = i0 + h;
            float2 t = tw[pos << (8 - stage)];
            float sn = INV ? -t.y : t.y;
            float2 a0 = s[i0], a1 = s[i1];
            bfly(a0, a1, t.x, sn);
            s[i0] = a0; s[i1] = a1;
        }
        __syncthreads();
    }
}

// Batched FFT along the outer axis: N rows x C cols, transform down columns,
// rows pre-bit-reversed. Block-wide, NT threads.
template<int LOGN, bool INV, int NT, int LOGC>
__device__ __forceinline__ void fft_outer(float2* s, const float2* tw) {
    constexpr int N = 1 << LOGN, C = 1 << LOGC;
#pragma unroll
    for (int stage = 1; stage <= LOGN; ++stage) {
        const int h = 1 << (stage - 1);
        const int total = (N / 2) * C;
        for (int idx = threadIdx.x; idx < total; idx += NT) {
            int col = idx & (C - 1);
            int q   = idx >> LOGC;
            int pos = q & (h - 1);
            int row0 = ((q >> (stage - 1)) << stage) + pos;
            int i0 = (row0 << LOGC) + col;
            int i1 = i0 + (h << LOGC);
            float2 t = tw[pos << (8 - stage)];
            float sn = INV ? -t.y : t.y;
            float2 a0 = s[i0], a1 = s[i1];
            bfly(a0, a1, t.x, sn);
            s[i0] = a0; s[i1] = a1;
        }
        __syncthreads();
    }
}

// Re P[r][c] from padded real table Rr (128 x 64, ld 65), c in [0,128).
__device__ __forceinline__ float rgetT(const float* Rr, int r, int c) {
    if (c >= 64) {
        r = (128 - r) & 127;
        c = 128 - c;
        if (c == 64) c = 63;   // only reachable for unused output row n=64
    }
    return Rr[r * 65 + c];
}

// ---------------------------------------------------------------------------
// Fused kernel path: per image (c1,c2): rfft2 of raw 128x128 kernel, then
// frequency-domain D4 symmetrization -> REAL K (128 x 64) float.
// K[n,k] = 0.25*(Re P[n,k] + Re P[-n,k] + Re P[k,n'] + Re P[-k,n'])
// ---------------------------------------------------------------------------
__global__ __launch_bounds__(512) void kfft(const float* __restrict__ kin,
                                            float* __restrict__ kout) {
    __shared__ float2 A[8192];    // 64 KB: row-FFT buffer, later Rr (float, padded)
    __shared__ float2 Bs[8192];   // 64 KB: column spectrum
    __shared__ float2 tw[128];
    int img = blockIdx.x;
    tw_init(tw);
    const float2* in2 = (const float2*)(kin + (size_t)img * 16384);
    // load rows, fold 6-bit col bit-reversal into the LDS scatter
    for (int idx = threadIdx.x; idx < 8192; idx += 512) {
        int r = idx >> 6, c = idx & 63;
        int bc = __brev((unsigned)c) >> 26;
        A[(r << 6) + bc] = in2[idx];
    }
    __syncthreads();
    // 128 row cfft64 (z[n] = x[2n] + i x[2n+1])
    fft_inner<6, false, 512>(A, 128, tw);
    // unpack rfft128 per row -> X[0..63], scatter rows bit-reversed (7-bit) into Bs
    for (int idx = threadIdx.x; idx < 4096; idx += 512) {
        int r = idx >> 5, kk = idx & 31;
        const float2* zr = A + (r << 6);
        float2* xo = Bs + ((__brev((unsigned)r) >> 25) << 6);
        if (kk == 0) {
            float2 z0 = zr[0];
            xo[0]  = make_float2(z0.x + z0.y, 0.f);
            float2 z32 = zr[32];
            xo[32] = make_float2(z32.x, -z32.y);
        } else {
            float2 zk = zr[kk], zm = zr[64 - kk];
            float ar = zk.x + zm.x, ai = zk.y - zm.y;
            float br = zk.x - zm.x, bi = zk.y + zm.y;
            float2 t = tw[2 * kk];                    // exp(-i*pi*kk/64)
            float p = t.x * br - t.y * bi, q = t.x * bi + t.y * br;
            xo[kk]      = make_float2(0.5f * (ar + q),  0.5f * (ai - p));
            xo[64 - kk] = make_float2(0.5f * (ar - q),  0.5f * (-ai - p));
        }
    }
    __syncthreads();
    // 64 col cfft128
    fft_outer<7, false, 512, 6>(Bs, tw);
    // real part -> padded float table (ld 65) in A's space
    float* Rr = (float*)A;
    for (int idx = threadIdx.x; idx < 8192; idx += 512) {
        int n = idx >> 6, k = idx & 63;
        Rr[n * 65 + k] = Bs[idx].x;
    }
    __syncthreads();
    // frequency-domain D4 symmetrization, store real K
    float* ko = kout + (size_t)img * 8192;
    for (int idx = threadIdx.x; idx < 8192; idx += 512) {
        int n = idx >> 6, k = idx & 63;
        float t1 = Rr[n * 65 + k];
        float t2 = Rr[((128 - n) & 127) * 65 + k];
        float t3 = rgetT(Rr, k, n);
        float t4 = rgetT(Rr, (128 - k) & 127, n);
        ko[idx] = 0.25f * (t1 + t2 + t3 + t4);
    }
}

// ---------------------------------------------------------------------------
// f path stage 1: row rfft256 (wave per row, 4 rows/block), keep k=0..63.
// ---------------------------------------------------------------------------
__global__ __launch_bounds__(256) void rfft256(const float* __restrict__ f,
                                               float2* __restrict__ G) {
    __shared__ float2 sm[4][128];
    __shared__ float2 tw[128];
    tw_init(tw);
    int wave = threadIdx.x >> 6, lane = threadIdx.x & 63;
    int row  = blockIdx.x * 4 + wave;
    float2* s = sm[wave];
    const float2* x = (const float2*)(f + (size_t)row * 256);
    s[lane] = x[lane];
    s[lane + 64] = x[lane + 64];
    __syncthreads();
    // 7-bit bit-reversal (regs + barrier)
    float2 t0 = s[__brev((unsigned)lane) >> 25];
    float2 t1 = s[__brev((unsigned)(lane + 64)) >> 25];
    __syncthreads();
    s[lane] = t0; s[lane + 64] = t1;
    __syncthreads();
#pragma unroll
    for (int stage = 1; stage <= 7; ++stage) {
        int h = 1 << (stage - 1);
        int pos = lane & (h - 1);
        int i0 = ((lane >> (stage - 1)) << stage) + pos;
        int i1 = i0 + h;
        float2 t = tw[pos << (8 - stage)];
        float2 a0 = s[i0], a1 = s[i1];
        bfly(a0, a1, t.x, t.y);
        s[i0] = a0; s[i1] = a1;
        __syncthreads();
    }
    // unpack k = lane (M = 128)
    float2 zk = s[lane];
    float2 zm = s[(128 - lane) & 127];
    float ar = zk.x + zm.x, ai = zk.y - zm.y;
    float br = zk.x - zm.x, bi = zk.y + zm.y;
    float2 t = tw[lane];
    float p = t.x * br - t.y * bi, q = t.x * bi + t.y * br;
    G[(size_t)row * 64 + lane] = make_float2(0.5f * (ar + q), 0.5f * (ai - p));
}

// ---------------------------------------------------------------------------
// f path stage 2: col cfft256 on 16-col groups, truncate to signed 128-row
// set {0..63, 0, -63..-1}, scale 0.25.
// ---------------------------------------------------------------------------
__global__ __launch_bounds__(256) void fcol256(const float2* __restrict__ G,
                                               float2* __restrict__ FH) {
    __shared__ float2 S[4096];   // 256 rows x 16 cols
    __shared__ float2 tw[128];
    tw_init(tw);
    int img = blockIdx.x >> 2, cg = blockIdx.x & 3;
    const float2* src = G + (size_t)img * 16384 + cg * 16;
    for (int idx = threadIdx.x; idx < 4096; idx += 256) {
        int r = idx >> 4, c = idx & 15;
        S[((__brev((unsigned)r) >> 24) << 4) + c] = src[(size_t)r * 64 + c];
    }
    __syncthreads();
    fft_outer<8, false, 256, 4>(S, tw);
    float2* dst = FH + (size_t)img * 8192 + cg * 16;
    for (int idx = threadIdx.x; idx < 2048; idx += 256) {
        int orow = idx >> 4, c = idx & 15;
        int srow = orow < 64 ? orow : orow + 128;
        float2 v = S[(srow << 4) + c];
        if (orow == 64) v = make_float2(0.f, 0.f);
        dst[(size_t)orow * 64 + c] = make_float2(v.x * 0.25f, v.y * 0.25f);
    }
}

// ---------------------------------------------------------------------------
// Per-frequency contraction with REAL K: C[b,d,nk] = sum_c F[b,c,nk]*K[c,d,nk]
// ---------------------------------------------------------------------------
__global__ __launch_bounds__(256) void einsum_rk(const float2* __restrict__ F,
                                                 const float* __restrict__ K,
                                                 float2* __restrict__ C) {
    int bid = blockIdx.x;
    int nkg = bid & 127, bh = (bid >> 7) & 1, dq = bid >> 8;
    int lane = threadIdx.x & 63, wave = threadIdx.x >> 6;
    int b  = bh * 4 + wave;
    int nk = nkg * 64 + lane;
    float2 Freg[16];
#pragma unroll
    for (int c = 0; c < 16; ++c) Freg[c] = F[(size_t)(b * 16 + c) * 8192 + nk];
#pragma unroll
    for (int dd = 0; dd < 8; ++dd) {
        int d = dq * 8 + dd;
        float2 acc = make_float2(0.f, 0.f);
#pragma unroll
        for (int c = 0; c < 16; ++c) {
            float w = K[(size_t)(c * 32 + d) * 8192 + nk];
            acc.x += Freg[c].x * w;
            acc.y += Freg[c].y * w;
        }
        C[(size_t)(b * 32 + d) * 8192 + nk] = acc;
    }
}

// ---------------------------------------------------------------------------
// Fused inverse: per image: col icfft128, row pack + icfft64 -> 128x128 reals.
// img < 128 -> FHAT -> out0; else CONV -> out1 (contiguous at out+img*16384).
// ---------------------------------------------------------------------------
__global__ __launch_bounds__(256) void ifuse(const float2* __restrict__ FH,
                                             const float2* __restrict__ CV,
                                             float* __restrict__ out) {
    __shared__ float2 S[8192];
    __shared__ float2 tw[128];
    tw_init(tw);
    int img = blockIdx.x;
    const float2* src = (img < 128) ? (FH + (size_t)img * 8192)
                                    : (CV + (size_t)(img - 128) * 8192);
    float2* dst = (float2*)(out + (size_t)img * 16384);
    for (int idx = threadIdx.x; idx < 8192; idx += 256) {
        int r = idx >> 6, c = idx & 63;
        S[((__brev((unsigned)r) >> 25) << 6) + c] = src[idx];
    }
    __syncthreads();
    fft_outer<7, true, 256, 6>(S, tw);
    // pack each row: X[0..63] (X[64]=0) -> Z[0..63], in place (pair slots)
    for (int idx = threadIdx.x; idx < 4096; idx += 256) {
        int r = idx >> 5, kk = idx & 31;
        float2* xr = S + (r << 6);
        if (kk == 0) {
            float2 X0 = xr[0];
            xr[0]  = make_float2(0.5f * (X0.x - X0.y), 0.5f * (X0.y + X0.x));
            float2 X32 = xr[32];
            xr[32] = make_float2(X32.x, -X32.y);
        } else {
            float2 Xk = xr[kk], Xm = xr[64 - kk];
            float er = 0.5f * (Xk.x + Xm.x), ei = 0.5f * (Xk.y - Xm.y);
            float br = 0.5f * (Xk.x - Xm.x), bi = 0.5f * (Xk.y + Xm.y);
            float2 t = tw[2 * kk];
            float cs = t.x, sn = -t.y;                 // exp(+i*pi*kk/64)
            float orr = cs * br - sn * bi, oi = cs * bi + sn * br;
            xr[kk]      = make_float2(er - oi,  ei + orr);
            xr[64 - kk] = make_float2(er + oi, -ei + orr);
        }
    }
    __syncthreads();
    // 6-bit col bit-reversal via disjoint pair swaps
    for (int idx = threadIdx.x; idx < 8192; idx += 256) {
        int r = idx >> 6, c = idx & 63;
        int bc = __brev((unsigned)c) >> 26;
        if (c < bc) {
            float2 a = S[(r << 6) + c], b2 = S[(r << 6) + bc];
            S[(r << 6) + c] = b2; S[(r << 6) + bc] = a;
        }
    }
    __syncthreads();
    fft_inner<6, true, 256>(S, 128, tw);
    for (int idx = threadIdx.x; idx < 8192; idx += 256) {
        float2 v = S[idx];
        dst[idx] = make_float2(v.x * (1.0f / 8192.0f), v.y * (1.0f / 8192.0f));
    }
}

// ---------------------------------------------------------------------------
// Launch
// ---------------------------------------------------------------------------
extern "C" void kernel_launch(void* const* d_in, const int* in_sizes, int n_in,
                              void* d_out, int out_size, void* d_ws, size_t ws_size,
                              hipStream_t stream) {
    const float* f   = (const float*)d_in[0];   // (8,16,256,256)
    const float* kin = (const float*)d_in[1];   // (1,16,32,128,128)
    float* out = (float*)d_out;                 // (8,16,128,128) | (8,32,128,128)
    char* ws = (char*)d_ws;

    // workspace:
    //   [0, 16777216)         : G (128,256,64 c64) -> then CONV (256,128,64 c64)
    //   [16777216, 25165824)  : FHAT (128,128,64 c64)
    //   [33554432, 50331648)  : Kr (512,128,64 f32)
    float2* G    = (float2*)ws;
    float2* CONV = (float2*)ws;
    float2* FHAT = (float2*)(ws + 16777216);
    float*  Kr   = (float*)(ws + 33554432);

    kfft<<<512, 512, 0, stream>>>(kin, Kr);
    rfft256<<<8192, 256, 0, stream>>>(f, G);
    fcol256<<<512, 256, 0, stream>>>(G, FHAT);
    einsum_rk<<<1024, 256, 0, stream>>>(FHAT, Kr, CONV);
    ifuse<<<384, 256, 0, stream>>>(FHAT, CONV, out);
}

// Round 5
// 188.941 us; speedup vs baseline: 2.3732x; 1.1255x over previous
//
#include <hip/hip_runtime.h>

#define PI_F 3.14159265358979f

// ---------------------------------------------------------------------------
// complex helpers
// ---------------------------------------------------------------------------
__device__ __forceinline__ float2 cmul(float2 a, float2 b) {
    return make_float2(a.x * b.x - a.y * b.y, a.x * b.y + a.y * b.x);
}
__device__ __forceinline__ float2 cadd(float2 a, float2 b) { return make_float2(a.x + b.x, a.y + b.y); }
__device__ __forceinline__ float2 csub(float2 a, float2 b) { return make_float2(a.x - b.x, a.y - b.y); }
__device__ __forceinline__ float2 shflx(float2 v, int m) {
    return make_float2(__shfl_xor(v.x, m, 64), __shfl_xor(v.y, m, 64));
}
__device__ __forceinline__ float2 shfli(float2 v, int src) {
    return make_float2(__shfl(v.x, src, 64), __shfl(v.y, src, 64));
}
__device__ __forceinline__ int brev6(int x) { return (int)(__brev((unsigned)x) >> 26); }

// Per-lane twiddles for the 6 shuffle DIF stages (m = 32,16,8,4,2,1).
// Upper lane (lane&m): W = exp(s*i*pi*pos/m), pos = lane&(m-1); lower: identity.
// sg = +1 lower (v' = p+v), -1 upper (v' = (p-v)*W).
template<bool INV>
__device__ __forceinline__ void tw_init(int lane, float2* w, float* sg) {
#pragma unroll
    for (int t = 0; t < 6; ++t) {
        int m = 32 >> t;
        bool up = (lane & m) != 0;
        int pos = lane & (m - 1);
        float ang = (INV ? PI_F : -PI_F) * (float)pos / (float)m;
        float sn, cs;
        __sincosf(ang, &sn, &cs);
        w[t]  = up ? make_float2(cs, sn) : make_float2(1.f, 0.f);
        sg[t] = up ? -1.f : 1.f;
    }
}

// 64-pt DIF FFT across the wave, 1 elem/lane. Natural in; out: lane l holds X[brev6(l)].
__device__ __forceinline__ float2 fft64s(float2 v, const float2* w, const float* sg) {
#pragma unroll
    for (int t = 0; t < 6; ++t) {
        int m = 32 >> t;
        float2 p = shflx(v, m);
        float2 d = make_float2(fmaf(sg[t], v.x, p.x), fmaf(sg[t], v.y, p.y));
        v = cmul(d, w[t]);
    }
    return v;
}

// ---------------------------------------------------------------------------
// Fused kernel path (one block per (c1,c2) image): rfft2(128x128) in regs +
// frequency-domain D4 symmetrization -> real K (128 x 64).
// ---------------------------------------------------------------------------
__global__ __launch_bounds__(512) void kfft(const float* __restrict__ kin,
                                            float* __restrict__ kout) {
    __shared__ float2 X[128 * 65];              // 66,560 B; later Rr = float[128*65]
    int img = blockIdx.x;
    int lane = threadIdx.x & 63, wv = threadIdx.x >> 6;   // 8 waves
    float2 w[6]; float sg[6];
    tw_init<false>(lane, w, sg);
    float sn, cs;
    __sincosf(-PI_F * (float)lane * (1.0f / 64.0f), &sn, &cs);
    float2 w64 = make_float2(cs, sn);           // unpack (M=64) AND col intra-stage twiddle
    const float2* in2 = (const float2*)(kin + (size_t)img * 16384);
    int b6 = brev6(lane);
    int gm = (64 - lane) & 63;
    // ---- row phase: 16 rows per wave, rfft128 via cfft64 in regs ----
#pragma unroll 2
    for (int rr = 0; rr < 16; ++rr) {
        int r = wv * 16 + rr;
        float2 z = in2[r * 64 + lane];          // z[lane] = (x[2l], x[2l+1])
        z = fft64s(z, w, sg);
        z = shfli(z, b6);                       // natural order: lane l = Z[l]
        float2 zm = shfli(z, gm);               // Z[(64-l)&63]
        float ar = z.x + zm.x, ai = z.y - zm.y;
        float br = z.x - zm.x, bi = z.y + zm.y;
        float p = w64.x * br - w64.y * bi, q = w64.x * bi + w64.y * br;
        X[r * 65 + lane] = make_float2(0.5f * (ar + q), 0.5f * (ai - p));
    }
    __syncthreads();
    // ---- col phase: 8 cols per wave, cfft128 (2 regs/lane) ----
    float2 c0[8], c1[8];
#pragma unroll
    for (int cc = 0; cc < 8; ++cc) {
        int k = wv * 8 + cc;
        c0[cc] = X[lane * 65 + k];
        c1[cc] = X[(lane + 64) * 65 + k];
    }
    __syncthreads();                            // all X reads done; reuse LDS as Rr
    float* Rr = (float*)X;
#pragma unroll
    for (int cc = 0; cc < 8; ++cc) {
        int k = wv * 8 + cc;
        float2 r0 = c0[cc], r1 = c1[cc];
        float2 t = r0;
        r0 = cadd(t, r1);
        r1 = cmul(csub(t, r1), w64);            // intra stage m=64, fwd
        r0 = fft64s(r0, w, sg);
        r1 = fft64s(r1, w, sg);
        // P[2*brev6(l)][k] = r0, P[2*brev6(l)+1][k] = r1
        Rr[(2 * b6) * 65 + k]     = r0.x;
        Rr[(2 * b6 + 1) * 65 + k] = r1.x;
    }
    __syncthreads();
    // ---- frequency-domain D4 symmetrization ----
    float* ko = kout + (size_t)img * 8192;
    for (int i = threadIdx.x; i < 8192; i += 512) {
        int n = i >> 6, k = i & 63;
        float t1 = Rr[n * 65 + k];
        float t2 = Rr[((128 - n) & 127) * 65 + k];
        float t3, t4;
        if (n < 64) {
            t3 = Rr[k * 65 + n];
            t4 = Rr[((128 - k) & 127) * 65 + n];
        } else {
            int c = 128 - n; if (c > 63) c = 63;   // n==64 unused downstream
            t3 = Rr[((128 - k) & 127) * 65 + c];
            t4 = Rr[k * 65 + c];
        }
        ko[i] = 0.25f * (t1 + t2 + t3 + t4);
    }
}

// ---------------------------------------------------------------------------
// f path stage 1: row rfft256 via cfft128 in regs. One wave per row.
// 32768 rows total -> 8192 blocks of 4 waves.
// ---------------------------------------------------------------------------
__global__ __launch_bounds__(256) void rfft256(const float* __restrict__ f,
                                               float2* __restrict__ G) {
    int lane = threadIdx.x & 63, wv = threadIdx.x >> 6;
    int row = blockIdx.x * 4 + wv;
    float2 w[6]; float sg[6];
    tw_init<false>(lane, w, sg);
    float sn, cs;
    __sincosf(-PI_F * (float)lane * (1.0f / 64.0f), &sn, &cs);
    float2 w64 = make_float2(cs, sn);
    __sincosf(-PI_F * (float)lane * (1.0f / 128.0f), &sn, &cs);
    float2 wu = make_float2(cs, sn);            // unpack M=128
    const float2* x = (const float2*)(f + (size_t)row * 256);
    float2 r0 = x[lane], r1 = x[lane + 64];
    float2 t = r0;
    r0 = cadd(t, r1);
    r1 = cmul(csub(t, r1), w64);
    r0 = fft64s(r0, w, sg);
    r1 = fft64s(r1, w, sg);
    // r0[l] = Z[2*brev6(l)], r1[l] = Z[2*brev6(l)+1]; gather Z[k], Z[128-k]
    int srcK = brev6(lane >> 1);
    int srcM = brev6((64 - ((lane + 1) >> 1)) & 63);
    float2 e0 = shfli(r0, srcK), o0 = shfli(r1, srcK);
    float2 zk = (lane & 1) ? o0 : e0;
    float2 e1 = shfli(r0, srcM), o1 = shfli(r1, srcM);
    float2 zm = (lane & 1) ? o1 : e1;
    float ar = zk.x + zm.x, ai = zk.y - zm.y;
    float br = zk.x - zm.x, bi = zk.y + zm.y;
    float p = wu.x * br - wu.y * bi, q = wu.x * bi + wu.y * br;
    G[(size_t)row * 64 + lane] = make_float2(0.5f * (ar + q), 0.5f * (ai - p));
}

// ---------------------------------------------------------------------------
// f path stage 2: col cfft256 (4 regs/lane), truncate to signed 128-row set,
// scale 0.25. One block per (image, 32-col half).
// ---------------------------------------------------------------------------
__global__ __launch_bounds__(512) void fcol256(const float2* __restrict__ G,
                                               float2* __restrict__ FH) {
    __shared__ float2 S[256 * 33];              // 67,584 B
    int img = blockIdx.x >> 1, h = blockIdx.x & 1;
    int lane = threadIdx.x & 63, wv = threadIdx.x >> 6;   // 8 waves
    float2 w[6]; float sg[6];
    tw_init<false>(lane, w, sg);
    float sn, cs;
    __sincosf(-PI_F * (float)lane * (1.0f / 64.0f), &sn, &cs);
    float2 w64 = make_float2(cs, sn);
    __sincosf(-PI_F * (float)lane * (1.0f / 128.0f), &sn, &cs);
    float2 w128a = make_float2(cs, sn);
    __sincosf(-PI_F * (float)(lane + 64) * (1.0f / 128.0f), &sn, &cs);
    float2 w128b = make_float2(cs, sn);
    const float2* src = G + (size_t)img * 16384 + h * 32;
    for (int i = threadIdx.x; i < 8192; i += 512) {
        int r = i >> 5, c = i & 31;
        S[r * 33 + c] = src[(size_t)r * 64 + c];
    }
    __syncthreads();
    float2 q0[4], q1[4], q2[4], q3[4];
#pragma unroll
    for (int cc = 0; cc < 4; ++cc) {
        int c = wv * 4 + cc;
        q0[cc] = S[(lane)       * 33 + c];
        q1[cc] = S[(lane +  64) * 33 + c];
        q2[cc] = S[(lane + 128) * 33 + c];
        q3[cc] = S[(lane + 192) * 33 + c];
    }
    __syncthreads();                            // reads done; reuse S for output staging
    int b6 = brev6(lane);
#pragma unroll
    for (int cc = 0; cc < 4; ++cc) {
        int c = wv * 4 + cc;
        float2 r0 = q0[cc], r1 = q1[cc], r2 = q2[cc], r3 = q3[cc], t;
        // stage m=128 (intra-lane)
        t = r0; r0 = cadd(t, r2); r2 = cmul(csub(t, r2), w128a);
        t = r1; r1 = cadd(t, r3); r3 = cmul(csub(t, r3), w128b);
        // stage m=64 (intra-lane)
        t = r0; r0 = cadd(t, r1); r1 = cmul(csub(t, r1), w64);
        t = r2; r2 = cadd(t, r3); r3 = cmul(csub(t, r3), w64);
        r0 = fft64s(r0, w, sg); r1 = fft64s(r1, w, sg);
        r2 = fft64s(r2, w, sg); r3 = fft64s(r3, w, sg);
        // reg j, lane l -> X[4*brev6(l) + brev2(j)]; keep n<64 (r=n) or n>=193 (r=n-128)
        float2 vv[4] = { r0, r2, r1, r3 };      // brev2 order: n = 4*b6 + j'
#pragma unroll
        for (int j = 0; j < 4; ++j) {
            int n = 4 * b6 + j;
            int r = (n < 64) ? n : ((n >= 193) ? n - 128 : -1);
            if (r >= 0) S[r * 33 + c] = make_float2(vv[j].x * 0.25f, vv[j].y * 0.25f);
        }
    }
    __syncthreads();
    float2* dst = FH + (size_t)img * 8192 + h * 32;
    for (int i = threadIdx.x; i < 4096; i += 512) {
        int r = i >> 5, c = i & 31;
        float2 v = (r == 64) ? make_float2(0.f, 0.f) : S[r * 33 + c];
        dst[(size_t)r * 64 + c] = v;
    }
}

// ---------------------------------------------------------------------------
// Per-frequency contraction, K read once: grid {nkg 256} x {dh 2}.
// C[b,d,nk] = sum_c F[b,c,nk] * K[c,d,nk] (K real).
// ---------------------------------------------------------------------------
__global__ __launch_bounds__(256) void einsum_rk(const float2* __restrict__ F,
                                                 const float* __restrict__ K,
                                                 float2* __restrict__ C) {
    __shared__ float2 Ft[128 * 32];             // 32 KB
    int nkg = blockIdx.x >> 1, dh = blockIdx.x & 1;
    int nk0 = nkg * 32;
    int t = threadIdx.x;
    for (int i = t; i < 4096; i += 256) {
        int bc = i >> 5, nl = i & 31;
        Ft[i] = F[(size_t)bc * 8192 + nk0 + nl];
    }
    __syncthreads();
    int nl = t & 31;
    int dg = t >> 5;                            // 0..7
    int nk = nk0 + nl;
#pragma unroll
    for (int dd = 0; dd < 2; ++dd) {
        int d = dh * 16 + dd * 8 + dg;
        float2 acc[8] = {};
#pragma unroll
        for (int c = 0; c < 16; ++c) {
            float kv = K[(size_t)(c * 32 + d) * 8192 + nk];
#pragma unroll
            for (int b = 0; b < 8; ++b) {
                float2 fv = Ft[(b * 16 + c) * 32 + nl];
                acc[b].x += fv.x * kv;
                acc[b].y += fv.y * kv;
            }
        }
#pragma unroll
        for (int b = 0; b < 8; ++b)
            C[(size_t)(b * 32 + d) * 8192 + nk] = acc[b];
    }
}

// ---------------------------------------------------------------------------
// Fused inverse (one block per output image): col icfft128 in regs, row pack +
// icfft64 in regs -> 128x128 reals, scaled 1/8192.
// ---------------------------------------------------------------------------
__global__ __launch_bounds__(512) void ifuse(const float2* __restrict__ FH,
                                             const float2* __restrict__ CV,
                                             float* __restrict__ out) {
    __shared__ float2 S[128 * 65];              // 66,560 B
    int img = blockIdx.x;
    int lane = threadIdx.x & 63, wv = threadIdx.x >> 6;   // 8 waves
    float2 w[6]; float sg[6];
    tw_init<true>(lane, w, sg);
    float sn, cs;
    __sincosf(PI_F * (float)lane * (1.0f / 64.0f), &sn, &cs);
    float2 w64 = make_float2(cs, sn);           // inverse intra-stage AND pack twiddle
    const float2* src = (img < 128) ? (FH + (size_t)img * 8192)
                                    : (CV + (size_t)(img - 128) * 8192);
    float2* dst = (float2*)(out + (size_t)img * 16384);
    for (int i = threadIdx.x; i < 8192; i += 512) {
        int r = i >> 6, c = i & 63;
        S[r * 65 + c] = src[i];
    }
    __syncthreads();
    float2 c0[8], c1[8];
#pragma unroll
    for (int cc = 0; cc < 8; ++cc) {
        int k = wv * 8 + cc;
        c0[cc] = S[lane * 65 + k];
        c1[cc] = S[(lane + 64) * 65 + k];
    }
    __syncthreads();
    int b6 = brev6(lane);
#pragma unroll
    for (int cc = 0; cc < 8; ++cc) {
        int k = wv * 8 + cc;
        float2 r0 = c0[cc], r1 = c1[cc];
        float2 t = r0;
        r0 = cadd(t, r1);
        r1 = cmul(csub(t, r1), w64);
        r0 = fft64s(r0, w, sg);
        r1 = fft64s(r1, w, sg);
        // spatial row m = 2*brev6(l) (+1); write back in place (column k)
        S[(2 * b6) * 65 + k]     = r0;
        S[(2 * b6 + 1) * 65 + k] = r1;
    }
    __syncthreads();
    // ---- row phase: irfft128 via icfft64, 16 rows per wave ----
#pragma unroll 2
    for (int rr = 0; rr < 16; ++rr) {
        int m = wv * 16 + rr;
        float2 X = S[m * 65 + lane];
        float2 Xm = shfli(X, (64 - lane) & 63);
        if (lane == 0) Xm = make_float2(0.f, 0.f);   // X[64] == 0
        float er = 0.5f * (X.x + Xm.x), ei = 0.5f * (X.y - Xm.y);
        float br = 0.5f * (X.x - Xm.x), bi = 0.5f * (X.y + Xm.y);
        float orr = w64.x * br - w64.y * bi, oi = w64.x * bi + w64.y * br;
        float2 Z = make_float2(er - oi, ei + orr);
        Z = fft64s(Z, w, sg);
        Z = shfli(Z, b6);                       // natural order
        dst[m * 64 + lane] = make_float2(Z.x * (1.0f / 8192.0f), Z.y * (1.0f / 8192.0f));
    }
}

// ---------------------------------------------------------------------------
// Launch
// ---------------------------------------------------------------------------
extern "C" void kernel_launch(void* const* d_in, const int* in_sizes, int n_in,
                              void* d_out, int out_size, void* d_ws, size_t ws_size,
                              hipStream_t stream) {
    const float* f   = (const float*)d_in[0];   // (8,16,256,256)
    const float* kin = (const float*)d_in[1];   // (1,16,32,128,128)
    float* out = (float*)d_out;                 // (8,16,128,128) | (8,32,128,128)
    char* ws = (char*)d_ws;

    // workspace:
    //   [0, 16777216)         : G (128,256,64 c64) -> then CONV (256,128,64 c64)
    //   [16777216, 25165824)  : FHAT (128,128,64 c64)
    //   [33554432, 50331648)  : Kr (512,128,64 f32)
    float2* G    = (float2*)ws;
    float2* CONV = (float2*)ws;
    float2* FHAT = (float2*)(ws + 16777216);
    float*  Kr   = (float*)(ws + 33554432);

    kfft<<<512, 512, 0, stream>>>(kin, Kr);
    rfft256<<<8192, 256, 0, stream>>>(f, G);    // 32768 rows / 4 per block
    fcol256<<<256, 512, 0, stream>>>(G, FHAT);
    einsum_rk<<<512, 256, 0, stream>>>(FHAT, Kr, CONV);
    ifuse<<<384, 512, 0, stream>>>(FHAT, CONV, out);
}

// Round 6
// 181.728 us; speedup vs baseline: 2.4674x; 1.0397x over previous
//
#include <hip/hip_runtime.h>

#define PI_F 3.14159265358979f

// ---------------------------------------------------------------------------
// complex helpers
// ---------------------------------------------------------------------------
__device__ __forceinline__ float2 cmul(float2 a, float2 b) {
    return make_float2(a.x * b.x - a.y * b.y, a.x * b.y + a.y * b.x);
}
__device__ __forceinline__ float2 cadd(float2 a, float2 b) { return make_float2(a.x + b.x, a.y + b.y); }
__device__ __forceinline__ float2 csub(float2 a, float2 b) { return make_float2(a.x - b.x, a.y - b.y); }
__device__ __forceinline__ float2 shflx(float2 v, int m) {
    return make_float2(__shfl_xor(v.x, m, 64), __shfl_xor(v.y, m, 64));
}
__device__ __forceinline__ float2 shfli(float2 v, int src) {
    return make_float2(__shfl(v.x, src, 64), __shfl(v.y, src, 64));
}
__device__ __forceinline__ int brev6(int x) { return (int)(__brev((unsigned)x) >> 26); }

// Per-lane twiddles for the 6 shuffle DIF stages (m = 32,16,8,4,2,1).
template<bool INV>
__device__ __forceinline__ void tw_init(int lane, float2* w, float* sg) {
#pragma unroll
    for (int t = 0; t < 6; ++t) {
        int m = 32 >> t;
        bool up = (lane & m) != 0;
        int pos = lane & (m - 1);
        float ang = (INV ? PI_F : -PI_F) * (float)pos / (float)m;
        float sn, cs;
        __sincosf(ang, &sn, &cs);
        w[t]  = up ? make_float2(cs, sn) : make_float2(1.f, 0.f);
        sg[t] = up ? -1.f : 1.f;
    }
}

// 64-pt DIF FFT across the wave, 1 elem/lane. Natural in; out: lane l holds X[brev6(l)].
__device__ __forceinline__ float2 fft64s(float2 v, const float2* w, const float* sg) {
#pragma unroll
    for (int t = 0; t < 6; ++t) {
        int m = 32 >> t;
        float2 p = shflx(v, m);
        float2 d = make_float2(fmaf(sg[t], v.x, p.x), fmaf(sg[t], v.y, p.y));
        v = cmul(d, w[t]);
    }
    return v;
}

// ---------------------------------------------------------------------------
// Fused kernel path (one block per (c1,c2) image): rfft2(128x128) in regs +
// frequency-domain D4 symmetrization -> real K (128 x 64).
// ---------------------------------------------------------------------------
__global__ __launch_bounds__(512) void kfft(const float* __restrict__ kin,
                                            float* __restrict__ kout) {
    __shared__ float2 X[128 * 65];              // 66,560 B; later Rr = float[128*65]
    int img = blockIdx.x;
    int lane = threadIdx.x & 63, wv = threadIdx.x >> 6;   // 8 waves
    float2 w[6]; float sg[6];
    tw_init<false>(lane, w, sg);
    int b6 = brev6(lane);
    float sn, cs;
    __sincosf(-PI_F * (float)lane * (1.0f / 64.0f), &sn, &cs);
    float2 w64 = make_float2(cs, sn);           // col intra-stage twiddle (lane-based)
    __sincosf(-PI_F * (float)b6 * (1.0f / 64.0f), &sn, &cs);
    float2 wub = make_float2(cs, sn);           // rfft unpack twiddle at k = b6
    const float2* in2 = (const float2*)(kin + (size_t)img * 16384);
    int gm2 = brev6((64 - b6) & 63);            // lane holding Z[(64-b6)&63]
    // ---- row phase: 16 rows per wave, rfft128 via cfft64 in regs,
    //      unpack in bit-reversed order (k = b6), scatter into X ----
#pragma unroll 2
    for (int rr = 0; rr < 16; ++rr) {
        int r = wv * 16 + rr;
        float2 z = in2[r * 64 + lane];          // z[lane] = (x[2l], x[2l+1])
        z = fft64s(z, w, sg);                   // lane l holds Z[brev6(l)]
        float2 zm = shfli(z, gm2);              // Z[(64 - k) & 63], k = b6
        float ar = z.x + zm.x, ai = z.y - zm.y;
        float br = z.x - zm.x, bi = z.y + zm.y;
        float p = wub.x * br - wub.y * bi, q = wub.x * bi + wub.y * br;
        X[r * 65 + b6] = make_float2(0.5f * (ar + q), 0.5f * (ai - p));
    }
    __syncthreads();
    // ---- col phase: 8 cols per wave, cfft128 (2 regs/lane) ----
    float2 c0[8], c1[8];
#pragma unroll
    for (int cc = 0; cc < 8; ++cc) {
        int k = wv * 8 + cc;
        c0[cc] = X[lane * 65 + k];
        c1[cc] = X[(lane + 64) * 65 + k];
    }
    __syncthreads();                            // all X reads done; reuse LDS as Rr
    float* Rr = (float*)X;
#pragma unroll
    for (int cc = 0; cc < 8; ++cc) {
        int k = wv * 8 + cc;
        float2 r0 = c0[cc], r1 = c1[cc];
        float2 t = r0;
        r0 = cadd(t, r1);
        r1 = cmul(csub(t, r1), w64);            // intra stage m=64, fwd
        r0 = fft64s(r0, w, sg);
        r1 = fft64s(r1, w, sg);
        // P[2*brev6(l)][k] = r0, P[2*brev6(l)+1][k] = r1
        Rr[(2 * b6) * 65 + k]     = r0.x;
        Rr[(2 * b6 + 1) * 65 + k] = r1.x;
    }
    __syncthreads();
    // ---- frequency-domain D4 symmetrization (float4 stores) ----
    float4* ko4 = (float4*)(kout + (size_t)img * 8192);
    for (int i = threadIdx.x; i < 2048; i += 512) {
        int n = i >> 4, k4 = (i & 15) << 2;
        float4 o;
        float* op = (float*)&o;
#pragma unroll
        for (int m = 0; m < 4; ++m) {
            int k = k4 + m;
            float t1 = Rr[n * 65 + k];
            float t2 = Rr[((128 - n) & 127) * 65 + k];
            float t3, t4;
            if (n < 64) {
                t3 = Rr[k * 65 + n];
                t4 = Rr[((128 - k) & 127) * 65 + n];
            } else {
                int c2 = 128 - n; if (c2 > 63) c2 = 63;   // n==64 unused downstream
                t3 = Rr[((128 - k) & 127) * 65 + c2];
                t4 = Rr[k * 65 + c2];
            }
            op[m] = 0.25f * (t1 + t2 + t3 + t4);
        }
        ko4[i] = o;
    }
}

// ---------------------------------------------------------------------------
// f path stage 1: row rfft256 via cfft128 in regs. 8 rows per wave
// (twiddle setup amortized). 32768 rows -> 1024 blocks x 4 waves.
// ---------------------------------------------------------------------------
__global__ __launch_bounds__(256) void rfft256(const float* __restrict__ f,
                                               float2* __restrict__ G) {
    int lane = threadIdx.x & 63, wv = threadIdx.x >> 6;
    int row0 = (blockIdx.x * 4 + wv) * 8;
    float2 w[6]; float sg[6];
    tw_init<false>(lane, w, sg);
    float sn, cs;
    __sincosf(-PI_F * (float)lane * (1.0f / 64.0f), &sn, &cs);
    float2 w64 = make_float2(cs, sn);
    __sincosf(-PI_F * (float)lane * (1.0f / 128.0f), &sn, &cs);
    float2 wu = make_float2(cs, sn);            // unpack M=128
    int srcK = brev6(lane >> 1);
    int srcM = brev6((64 - ((lane + 1) >> 1)) & 63);
#pragma unroll 2
    for (int rr = 0; rr < 8; ++rr) {
        size_t row = (size_t)(row0 + rr);
        const float2* x = (const float2*)(f + row * 256);
        float2 r0 = x[lane], r1 = x[lane + 64];
        float2 t = r0;
        r0 = cadd(t, r1);
        r1 = cmul(csub(t, r1), w64);
        r0 = fft64s(r0, w, sg);
        r1 = fft64s(r1, w, sg);
        // r0[l] = Z[2*brev6(l)], r1[l] = Z[2*brev6(l)+1]; gather Z[k], Z[128-k]
        float2 e0 = shfli(r0, srcK), o0 = shfli(r1, srcK);
        float2 zk = (lane & 1) ? o0 : e0;
        float2 e1 = shfli(r0, srcM), o1 = shfli(r1, srcM);
        float2 zm = (lane & 1) ? o1 : e1;
        float ar = zk.x + zm.x, ai = zk.y - zm.y;
        float br = zk.x - zm.x, bi = zk.y + zm.y;
        float p = wu.x * br - wu.y * bi, q = wu.x * bi + wu.y * br;
        G[row * 64 + lane] = make_float2(0.5f * (ar + q), 0.5f * (ai - p));
    }
}

// ---------------------------------------------------------------------------
// f path stage 2: col cfft256 (4 regs/lane), truncate to signed 128-row set,
// scale 0.25. One block per (image, 32-col half).
// ---------------------------------------------------------------------------
__global__ __launch_bounds__(512) void fcol256(const float2* __restrict__ G,
                                               float2* __restrict__ FH) {
    __shared__ float2 S[256 * 33];              // 67,584 B
    int img = blockIdx.x >> 1, h = blockIdx.x & 1;
    int lane = threadIdx.x & 63, wv = threadIdx.x >> 6;   // 8 waves
    float2 w[6]; float sg[6];
    tw_init<false>(lane, w, sg);
    float sn, cs;
    __sincosf(-PI_F * (float)lane * (1.0f / 64.0f), &sn, &cs);
    float2 w64 = make_float2(cs, sn);
    __sincosf(-PI_F * (float)lane * (1.0f / 128.0f), &sn, &cs);
    float2 w128a = make_float2(cs, sn);
    __sincosf(-PI_F * (float)(lane + 64) * (1.0f / 128.0f), &sn, &cs);
    float2 w128b = make_float2(cs, sn);
    const float2* src = G + (size_t)img * 16384 + h * 32;
    for (int i = threadIdx.x; i < 8192; i += 512) {
        int r = i >> 5, c = i & 31;
        S[r * 33 + c] = src[(size_t)r * 64 + c];
    }
    __syncthreads();
    float2 q0[4], q1[4], q2[4], q3[4];
#pragma unroll
    for (int cc = 0; cc < 4; ++cc) {
        int c = wv * 4 + cc;
        q0[cc] = S[(lane)       * 33 + c];
        q1[cc] = S[(lane +  64) * 33 + c];
        q2[cc] = S[(lane + 128) * 33 + c];
        q3[cc] = S[(lane + 192) * 33 + c];
    }
    __syncthreads();                            // reads done; reuse S for output staging
    int b6 = brev6(lane);
#pragma unroll
    for (int cc = 0; cc < 4; ++cc) {
        int c = wv * 4 + cc;
        float2 r0 = q0[cc], r1 = q1[cc], r2 = q2[cc], r3 = q3[cc], t;
        // stage m=128 (intra-lane)
        t = r0; r0 = cadd(t, r2); r2 = cmul(csub(t, r2), w128a);
        t = r1; r1 = cadd(t, r3); r3 = cmul(csub(t, r3), w128b);
        // stage m=64 (intra-lane)
        t = r0; r0 = cadd(t, r1); r1 = cmul(csub(t, r1), w64);
        t = r2; r2 = cadd(t, r3); r3 = cmul(csub(t, r3), w64);
        r0 = fft64s(r0, w, sg); r1 = fft64s(r1, w, sg);
        r2 = fft64s(r2, w, sg); r3 = fft64s(r3, w, sg);
        // reg j, lane l -> X[4*brev6(l) + brev2(j)]; keep n<64 (r=n) or n>=193 (r=n-128)
        float2 vv[4] = { r0, r2, r1, r3 };      // brev2 order: n = 4*b6 + j'
#pragma unroll
        for (int j = 0; j < 4; ++j) {
            int n = 4 * b6 + j;
            int r = (n < 64) ? n : ((n >= 193) ? n - 128 : -1);
            if (r >= 0) S[r * 33 + c] = make_float2(vv[j].x * 0.25f, vv[j].y * 0.25f);
        }
    }
    __syncthreads();
    float2* dst = FH + (size_t)img * 8192 + h * 32;
    for (int i = threadIdx.x; i < 4096; i += 512) {
        int r = i >> 5, c = i & 31;
        float2 v = (r == 64) ? make_float2(0.f, 0.f) : S[r * 33 + c];
        dst[(size_t)r * 64 + c] = v;
    }
}

// ---------------------------------------------------------------------------
// Per-frequency contraction, single pass: F and K each read once.
// Grid 256 (one 32-nk group per block), 512 threads.
// C[b,d,nk] = sum_c F[b,c,nk] * K[c,d,nk] (K real).
// ---------------------------------------------------------------------------
__global__ __launch_bounds__(512) void einsum_rk(const float2* __restrict__ F,
                                                 const float* __restrict__ K,
                                                 float2* __restrict__ C) {
    __shared__ float2 Ft[128 * 32];             // 32 KB
    int nk0 = blockIdx.x * 32;
    int t = threadIdx.x;
    for (int i = t; i < 4096; i += 512) {
        int bc = i >> 5, nl = i & 31;
        Ft[i] = F[(size_t)bc * 8192 + nk0 + nl];
    }
    __syncthreads();
    int nl = t & 31, dg = t >> 5;               // dg 0..15
    int nk = nk0 + nl;
    float2 acc[2][8] = {};
#pragma unroll
    for (int c = 0; c < 16; ++c) {
        float2 fv[8];
#pragma unroll
        for (int b = 0; b < 8; ++b) fv[b] = Ft[(b * 16 + c) * 32 + nl];
#pragma unroll
        for (int j = 0; j < 2; ++j) {
            int d = j * 16 + dg;
            float kv = K[(size_t)(c * 32 + d) * 8192 + nk];
#pragma unroll
            for (int b = 0; b < 8; ++b) {
                acc[j][b].x = fmaf(fv[b].x, kv, acc[j][b].x);
                acc[j][b].y = fmaf(fv[b].y, kv, acc[j][b].y);
            }
        }
    }
#pragma unroll
    for (int j = 0; j < 2; ++j) {
        int d = j * 16 + dg;
#pragma unroll
        for (int b = 0; b < 8; ++b)
            C[(size_t)(b * 32 + d) * 8192 + nk] = acc[j][b];
    }
}

// ---------------------------------------------------------------------------
// Fused inverse (one block per output image): col icfft128 in regs, row pack +
// icfft64 in regs -> 128x128 reals, scaled 1/8192.
// ---------------------------------------------------------------------------
__global__ __launch_bounds__(512) void ifuse(const float2* __restrict__ FH,
                                             const float2* __restrict__ CV,
                                             float* __restrict__ out) {
    __shared__ float2 S[128 * 65];              // 66,560 B
    int img = blockIdx.x;
    int lane = threadIdx.x & 63, wv = threadIdx.x >> 6;   // 8 waves
    float2 w[6]; float sg[6];
    tw_init<true>(lane, w, sg);
    float sn, cs;
    __sincosf(PI_F * (float)lane * (1.0f / 64.0f), &sn, &cs);
    float2 w64 = make_float2(cs, sn);           // inverse intra-stage AND pack twiddle
    const float2* src = (img < 128) ? (FH + (size_t)img * 8192)
                                    : (CV + (size_t)(img - 128) * 8192);
    float2* dst = (float2*)(out + (size_t)img * 16384);
    for (int i = threadIdx.x; i < 8192; i += 512) {
        int r = i >> 6, c = i & 63;
        S[r * 65 + c] = src[i];
    }
    __syncthreads();
    float2 c0[8], c1[8];
#pragma unroll
    for (int cc = 0; cc < 8; ++cc) {
        int k = wv * 8 + cc;
        c0[cc] = S[lane * 65 + k];
        c1[cc] = S[(lane + 64) * 65 + k];
    }
    __syncthreads();
    int b6 = brev6(lane);
#pragma unroll
    for (int cc = 0; cc < 8; ++cc) {
        int k = wv * 8 + cc;
        float2 r0 = c0[cc], r1 = c1[cc];
        float2 t = r0;
        r0 = cadd(t, r1);
        r1 = cmul(csub(t, r1), w64);
        r0 = fft64s(r0, w, sg);
        r1 = fft64s(r1, w, sg);
        // spatial row m = 2*brev6(l) (+1); write back in place (column k)
        S[(2 * b6) * 65 + k]     = r0;
        S[(2 * b6 + 1) * 65 + k] = r1;
    }
    __syncthreads();
    // ---- row phase: irfft128 via icfft64, 16 rows per wave ----
#pragma unroll 2
    for (int rr = 0; rr < 16; ++rr) {
        int m = wv * 16 + rr;
        float2 X = S[m * 65 + lane];
        float2 Xm = shfli(X, (64 - lane) & 63);
        if (lane == 0) Xm = make_float2(0.f, 0.f);   // X[64] == 0
        float er = 0.5f * (X.x + Xm.x), ei = 0.5f * (X.y - Xm.y);
        float br = 0.5f * (X.x - Xm.x), bi = 0.5f * (X.y + Xm.y);
        float orr = w64.x * br - w64.y * bi, oi = w64.x * bi + w64.y * br;
        float2 Z = make_float2(er - oi, ei + orr);
        Z = fft64s(Z, w, sg);
        Z = shfli(Z, b6);                       // natural order
        dst[m * 64 + lane] = make_float2(Z.x * (1.0f / 8192.0f), Z.y * (1.0f / 8192.0f));
    }
}

// ---------------------------------------------------------------------------
// Launch
// ---------------------------------------------------------------------------
extern "C" void kernel_launch(void* const* d_in, const int* in_sizes, int n_in,
                              void* d_out, int out_size, void* d_ws, size_t ws_size,
                              hipStream_t stream) {
    const float* f   = (const float*)d_in[0];   // (8,16,256,256)
    const float* kin = (const float*)d_in[1];   // (1,16,32,128,128)
    float* out = (float*)d_out;                 // (8,16,128,128) | (8,32,128,128)
    char* ws = (char*)d_ws;

    // workspace:
    //   [0, 16777216)         : G (128,256,64 c64) -> then CONV (256,128,64 c64)
    //   [16777216, 25165824)  : FHAT (128,128,64 c64)
    //   [33554432, 50331648)  : Kr (512,128,64 f32)
    float2* G    = (float2*)ws;
    float2* CONV = (float2*)ws;
    float2* FHAT = (float2*)(ws + 16777216);
    float*  Kr   = (float*)(ws + 33554432);

    kfft<<<512, 512, 0, stream>>>(kin, Kr);
    rfft256<<<1024, 256, 0, stream>>>(f, G);    // 32768 rows / 32 per block
    fcol256<<<256, 512, 0, stream>>>(G, FHAT);
    einsum_rk<<<256, 512, 0, stream>>>(FHAT, Kr, CONV);
    ifuse<<<384, 512, 0, stream>>>(FHAT, CONV, out);
}

// Round 7
// 164.677 us; speedup vs baseline: 2.7229x; 1.1035x over previous
//
#include <hip/hip_runtime.h>

#define PI_F 3.14159265358979f

// ---------------------------------------------------------------------------
// complex helpers
// ---------------------------------------------------------------------------
__device__ __forceinline__ float2 cmul(float2 a, float2 b) {
    return make_float2(a.x * b.x - a.y * b.y, a.x * b.y + a.y * b.x);
}
__device__ __forceinline__ float2 cadd(float2 a, float2 b) { return make_float2(a.x + b.x, a.y + b.y); }
__device__ __forceinline__ float2 csub(float2 a, float2 b) { return make_float2(a.x - b.x, a.y - b.y); }
__device__ __forceinline__ float2 shflx(float2 v, int m) {
    return make_float2(__shfl_xor(v.x, m, 64), __shfl_xor(v.y, m, 64));
}
__device__ __forceinline__ float2 shfli(float2 v, int src) {
    return make_float2(__shfl(v.x, src, 64), __shfl(v.y, src, 64));
}
__device__ __forceinline__ int brev6(int x) { return (int)(__brev((unsigned)x) >> 26); }

// DPP cross-lane exchange (no LDS pipe): xor1 = quad_perm[1,0,3,2] (0xB1),
// xor2 = quad_perm[2,3,0,1] (0x4E), xor8 = row_ror:8 (0x128, within 16-lane row).
template<int CTRL>
__device__ __forceinline__ float dpp1(float x) {
    return __builtin_bit_cast(float, __builtin_amdgcn_update_dpp(
        0, __builtin_bit_cast(int, x), CTRL, 0xF, 0xF, true));
}
template<int CTRL>
__device__ __forceinline__ float2 dppx(float2 v) {
    return make_float2(dpp1<CTRL>(v.x), dpp1<CTRL>(v.y));
}
template<int M>
__device__ __forceinline__ float2 xorx(float2 v) {
    if constexpr (M == 1)      return dppx<0xB1>(v);
    else if constexpr (M == 2) return dppx<0x4E>(v);
    else if constexpr (M == 8) return dppx<0x128>(v);
    else                       return shflx(v, M);
}

// Per-lane twiddles for the 6 shuffle DIF stages (m = 32,16,8,4,2,1).
template<bool INV>
__device__ __forceinline__ void tw_init(int lane, float2* w, float* sg) {
#pragma unroll
    for (int t = 0; t < 6; ++t) {
        int m = 32 >> t;
        bool up = (lane & m) != 0;
        int pos = lane & (m - 1);
        float ang = (INV ? PI_F : -PI_F) * (float)pos / (float)m;
        float sn, cs;
        __sincosf(ang, &sn, &cs);
        w[t]  = up ? make_float2(cs, sn) : make_float2(1.f, 0.f);
        sg[t] = up ? -1.f : 1.f;
    }
}

// 64-pt DIF FFT across the wave, 1 elem/lane. Natural in; out: lane l holds X[brev6(l)].
__device__ __forceinline__ float2 fft64s(float2 v, const float2* w, const float* sg) {
#define FFT_STAGE(T, M) { float2 p = xorx<M>(v);                                   \
        float2 d = make_float2(fmaf(sg[T], v.x, p.x), fmaf(sg[T], v.y, p.y));      \
        v = cmul(d, w[T]); }
    FFT_STAGE(0, 32) FFT_STAGE(1, 16) FFT_STAGE(2, 8)
    FFT_STAGE(3, 4)  FFT_STAGE(4, 2)  FFT_STAGE(5, 1)
#undef FFT_STAGE
    return v;
}

// ---------------------------------------------------------------------------
// kfft body (one block per (c1,c2) image): rfft2(128x128) in regs +
// frequency-domain D4 symmetrization -> real K (128 x 64). 512 threads.
// ---------------------------------------------------------------------------
__device__ void kfft_body(const float* __restrict__ kin, float* __restrict__ kout,
                          float2* X, int img) {
    int lane = threadIdx.x & 63, wv = threadIdx.x >> 6;   // 8 waves
    float2 w[6]; float sg[6];
    tw_init<false>(lane, w, sg);
    int b6 = brev6(lane);
    float sn, cs;
    __sincosf(-PI_F * (float)lane * (1.0f / 64.0f), &sn, &cs);
    float2 w64 = make_float2(cs, sn);           // col intra-stage twiddle (lane-based)
    __sincosf(-PI_F * (float)b6 * (1.0f / 64.0f), &sn, &cs);
    float2 wub = make_float2(cs, sn);           // rfft unpack twiddle at k = b6
    const float2* in2 = (const float2*)(kin + (size_t)img * 16384);
    int gm2 = brev6((64 - b6) & 63);            // lane holding Z[(64-b6)&63]
    // ---- row phase: 16 rows per wave, rfft128 via cfft64 in regs ----
#pragma unroll 2
    for (int rr = 0; rr < 16; ++rr) {
        int r = wv * 16 + rr;
        float2 z = in2[r * 64 + lane];          // z[lane] = (x[2l], x[2l+1])
        z = fft64s(z, w, sg);                   // lane l holds Z[brev6(l)]
        float2 zm = shfli(z, gm2);              // Z[(64 - k) & 63], k = b6
        float ar = z.x + zm.x, ai = z.y - zm.y;
        float br = z.x - zm.x, bi = z.y + zm.y;
        float p = wub.x * br - wub.y * bi, q = wub.x * bi + wub.y * br;
        X[r * 65 + b6] = make_float2(0.5f * (ar + q), 0.5f * (ai - p));
    }
    __syncthreads();
    // ---- col phase: 8 cols per wave, cfft128 (2 regs/lane) ----
    float2 c0[8], c1[8];
#pragma unroll
    for (int cc = 0; cc < 8; ++cc) {
        int k = wv * 8 + cc;
        c0[cc] = X[lane * 65 + k];
        c1[cc] = X[(lane + 64) * 65 + k];
    }
    __syncthreads();                            // all X reads done; reuse LDS as Rr
    float* Rr = (float*)X;
#pragma unroll
    for (int cc = 0; cc < 8; ++cc) {
        int k = wv * 8 + cc;
        float2 r0 = c0[cc], r1 = c1[cc];
        float2 t = r0;
        r0 = cadd(t, r1);
        r1 = cmul(csub(t, r1), w64);            // intra stage m=64, fwd
        r0 = fft64s(r0, w, sg);
        r1 = fft64s(r1, w, sg);
        Rr[(2 * b6) * 65 + k]     = r0.x;
        Rr[(2 * b6 + 1) * 65 + k] = r1.x;
    }
    __syncthreads();
    // ---- frequency-domain D4 symmetrization (float4 stores) ----
    float4* ko4 = (float4*)(kout + (size_t)img * 8192);
    for (int i = threadIdx.x; i < 2048; i += 512) {
        int n = i >> 4, k4 = (i & 15) << 2;
        float4 o;
        float* op = (float*)&o;
#pragma unroll
        for (int m = 0; m < 4; ++m) {
            int k = k4 + m;
            float t1 = Rr[n * 65 + k];
            float t2 = Rr[((128 - n) & 127) * 65 + k];
            float t3, t4;
            if (n < 64) {
                t3 = Rr[k * 65 + n];
                t4 = Rr[((128 - k) & 127) * 65 + n];
            } else {
                int c2 = 128 - n; if (c2 > 63) c2 = 63;   // n==64 unused downstream
                t3 = Rr[((128 - k) & 127) * 65 + c2];
                t4 = Rr[k * 65 + c2];
            }
            op[m] = 0.25f * (t1 + t2 + t3 + t4);
        }
        ko4[i] = o;
    }
}

// ---------------------------------------------------------------------------
// fcol body: col cfft256 (4 regs/lane) on a 16-col group, truncate to signed
// 128-row set, scale 0.25. 512 threads; S stride 17 (2-way-free banks).
// ---------------------------------------------------------------------------
__device__ void fcol_body(const float2* __restrict__ G, float2* __restrict__ FH,
                          float2* S, int bid) {
    int img = bid >> 2, q = bid & 3;
    int lane = threadIdx.x & 63, wv = threadIdx.x >> 6;   // 8 waves
    float2 w[6]; float sg[6];
    tw_init<false>(lane, w, sg);
    float sn, cs;
    __sincosf(-PI_F * (float)lane * (1.0f / 64.0f), &sn, &cs);
    float2 w64 = make_float2(cs, sn);
    __sincosf(-PI_F * (float)lane * (1.0f / 128.0f), &sn, &cs);
    float2 w128a = make_float2(cs, sn);
    __sincosf(-PI_F * (float)(lane + 64) * (1.0f / 128.0f), &sn, &cs);
    float2 w128b = make_float2(cs, sn);
    const float2* src = G + (size_t)img * 16384 + q * 16;
    for (int i = threadIdx.x; i < 4096; i += 512) {
        int r = i >> 4, c = i & 15;
        S[r * 17 + c] = src[(size_t)r * 64 + c];
    }
    __syncthreads();
    float2 q0[2], q1[2], q2[2], q3[2];
#pragma unroll
    for (int cc = 0; cc < 2; ++cc) {
        int c = wv * 2 + cc;
        q0[cc] = S[(lane)       * 17 + c];
        q1[cc] = S[(lane +  64) * 17 + c];
        q2[cc] = S[(lane + 128) * 17 + c];
        q3[cc] = S[(lane + 192) * 17 + c];
    }
    __syncthreads();                            // reads done; reuse S for output staging
    int b6 = brev6(lane);
#pragma unroll
    for (int cc = 0; cc < 2; ++cc) {
        int c = wv * 2 + cc;
        float2 r0 = q0[cc], r1 = q1[cc], r2 = q2[cc], r3 = q3[cc], t;
        // stage m=128 (intra-lane)
        t = r0; r0 = cadd(t, r2); r2 = cmul(csub(t, r2), w128a);
        t = r1; r1 = cadd(t, r3); r3 = cmul(csub(t, r3), w128b);
        // stage m=64 (intra-lane)
        t = r0; r0 = cadd(t, r1); r1 = cmul(csub(t, r1), w64);
        t = r2; r2 = cadd(t, r3); r3 = cmul(csub(t, r3), w64);
        r0 = fft64s(r0, w, sg); r1 = fft64s(r1, w, sg);
        r2 = fft64s(r2, w, sg); r3 = fft64s(r3, w, sg);
        // reg j, lane l -> X[4*brev6(l) + brev2(j)]; keep n<64 (r=n) or n>=193 (r=n-128)
        float2 vv[4] = { r0, r2, r1, r3 };      // brev2 order: n = 4*b6 + j'
#pragma unroll
        for (int j = 0; j < 4; ++j) {
            int n = 4 * b6 + j;
            int r = (n < 64) ? n : ((n >= 193) ? n - 128 : -1);
            if (r >= 0) S[r * 17 + c] = make_float2(vv[j].x * 0.25f, vv[j].y * 0.25f);
        }
    }
    __syncthreads();
    float2* dst = FH + (size_t)img * 8192 + q * 16;
    for (int i = threadIdx.x; i < 2048; i += 512) {
        int r = i >> 4, c = i & 15;
        float2 v = (r == 64) ? make_float2(0.f, 0.f) : S[r * 17 + c];
        dst[(size_t)r * 64 + c] = v;
    }
}

// ---------------------------------------------------------------------------
// einsum body: C[b,d,nk] = sum_c F[b,c,nk] * K[c,d,nk] (K real); F,K read once.
// One 32-nk group per block, 512 threads.
// ---------------------------------------------------------------------------
__device__ void einsum_body(const float2* __restrict__ F, const float* __restrict__ K,
                            float2* __restrict__ C, float2* Ft, int bid) {
    int nk0 = bid * 32;
    int t = threadIdx.x;
    for (int i = t; i < 4096; i += 512) {
        int bc = i >> 5, nl = i & 31;
        Ft[i] = F[(size_t)bc * 8192 + nk0 + nl];
    }
    __syncthreads();
    int nl = t & 31, dg = t >> 5;               // dg 0..15
    int nk = nk0 + nl;
    float2 acc[2][8] = {};
#pragma unroll
    for (int c = 0; c < 16; ++c) {
        float2 fv[8];
#pragma unroll
        for (int b = 0; b < 8; ++b) fv[b] = Ft[(b * 16 + c) * 32 + nl];
#pragma unroll
        for (int j = 0; j < 2; ++j) {
            int d = j * 16 + dg;
            float kv = K[(size_t)(c * 32 + d) * 8192 + nk];
#pragma unroll
            for (int b = 0; b < 8; ++b) {
                acc[j][b].x = fmaf(fv[b].x, kv, acc[j][b].x);
                acc[j][b].y = fmaf(fv[b].y, kv, acc[j][b].y);
            }
        }
    }
#pragma unroll
    for (int j = 0; j < 2; ++j) {
        int d = j * 16 + dg;
#pragma unroll
        for (int b = 0; b < 8; ++b)
            C[(size_t)(b * 32 + d) * 8192 + nk] = acc[j][b];
    }
}

// ---------------------------------------------------------------------------
// ifuse body (one output image): col icfft128 in regs, row pack + icfft64 in
// regs -> 128x128 reals, scaled 1/8192. 512 threads.
// ---------------------------------------------------------------------------
__device__ void ifuse_body(const float2* __restrict__ src, float2* __restrict__ dst,
                           float2* S) {
    int lane = threadIdx.x & 63, wv = threadIdx.x >> 6;   // 8 waves
    float2 w[6]; float sg[6];
    tw_init<true>(lane, w, sg);
    float sn, cs;
    __sincosf(PI_F * (float)lane * (1.0f / 64.0f), &sn, &cs);
    float2 w64 = make_float2(cs, sn);           // inverse intra-stage AND pack twiddle
    for (int i = threadIdx.x; i < 8192; i += 512) {
        int r = i >> 6, c = i & 63;
        S[r * 65 + c] = src[i];
    }
    __syncthreads();
    float2 c0[8], c1[8];
#pragma unroll
    for (int cc = 0; cc < 8; ++cc) {
        int k = wv * 8 + cc;
        c0[cc] = S[lane * 65 + k];
        c1[cc] = S[(lane + 64) * 65 + k];
    }
    __syncthreads();
    int b6 = brev6(lane);
#pragma unroll
    for (int cc = 0; cc < 8; ++cc) {
        int k = wv * 8 + cc;
        float2 r0 = c0[cc], r1 = c1[cc];
        float2 t = r0;
        r0 = cadd(t, r1);
        r1 = cmul(csub(t, r1), w64);
        r0 = fft64s(r0, w, sg);
        r1 = fft64s(r1, w, sg);
        S[(2 * b6) * 65 + k]     = r0;
        S[(2 * b6 + 1) * 65 + k] = r1;
    }
    __syncthreads();
    // ---- row phase: irfft128 via icfft64, 16 rows per wave ----
#pragma unroll 2
    for (int rr = 0; rr < 16; ++rr) {
        int m = wv * 16 + rr;
        float2 X = S[m * 65 + lane];
        float2 Xm = shfli(X, (64 - lane) & 63);
        if (lane == 0) Xm = make_float2(0.f, 0.f);   // X[64] == 0
        float er = 0.5f * (X.x + Xm.x), ei = 0.5f * (X.y - Xm.y);
        float br = 0.5f * (X.x - Xm.x), bi = 0.5f * (X.y + Xm.y);
        float orr = w64.x * br - w64.y * bi, oi = w64.x * bi + w64.y * br;
        float2 Z = make_float2(er - oi, ei + orr);
        Z = fft64s(Z, w, sg);
        Z = shfli(Z, b6);                       // natural order
        dst[m * 64 + lane] = make_float2(Z.x * (1.0f / 8192.0f), Z.y * (1.0f / 8192.0f));
    }
}

// ---------------------------------------------------------------------------
// f path stage 1: row rfft256 via cfft128 in regs. 8 rows per wave.
// 32768 rows -> 1024 blocks x 4 waves.
// ---------------------------------------------------------------------------
__global__ __launch_bounds__(256) void rfft256(const float* __restrict__ f,
                                               float2* __restrict__ G) {
    int lane = threadIdx.x & 63, wv = threadIdx.x >> 6;
    int row0 = (blockIdx.x * 4 + wv) * 8;
    float2 w[6]; float sg[6];
    tw_init<false>(lane, w, sg);
    float sn, cs;
    __sincosf(-PI_F * (float)lane * (1.0f / 64.0f), &sn, &cs);
    float2 w64 = make_float2(cs, sn);
    __sincosf(-PI_F * (float)lane * (1.0f / 128.0f), &sn, &cs);
    float2 wu = make_float2(cs, sn);            // unpack M=128
    int srcK = brev6(lane >> 1);
    int srcM = brev6((64 - ((lane + 1) >> 1)) & 63);
#pragma unroll 2
    for (int rr = 0; rr < 8; ++rr) {
        size_t row = (size_t)(row0 + rr);
        const float2* x = (const float2*)(f + row * 256);
        float2 r0 = x[lane], r1 = x[lane + 64];
        float2 t = r0;
        r0 = cadd(t, r1);
        r1 = cmul(csub(t, r1), w64);
        r0 = fft64s(r0, w, sg);
        r1 = fft64s(r1, w, sg);
        float2 e0 = shfli(r0, srcK), o0 = shfli(r1, srcK);
        float2 zk = (lane & 1) ? o0 : e0;
        float2 e1 = shfli(r0, srcM), o1 = shfli(r1, srcM);
        float2 zm = (lane & 1) ? o1 : e1;
        float ar = zk.x + zm.x, ai = zk.y - zm.y;
        float br = zk.x - zm.x, bi = zk.y + zm.y;
        float p = wu.x * br - wu.y * bi, q = wu.x * bi + wu.y * br;
        G[row * 64 + lane] = make_float2(0.5f * (ar + q), 0.5f * (ai - p));
    }
}

// ---------------------------------------------------------------------------
// merged launches
// ---------------------------------------------------------------------------
__global__ __launch_bounds__(512) void mega1(const float* __restrict__ kin,
                                             float* __restrict__ Kr,
                                             const float2* __restrict__ G,
                                             float2* __restrict__ FH) {
    __shared__ float2 SH[128 * 65];             // 66,560 B (kfft X / fcol S)
    int bid = blockIdx.x;
    if (bid < 512) kfft_body(kin, Kr, SH, bid);
    else           fcol_body(G, FH, SH, bid - 512);
}

__global__ __launch_bounds__(512) void mega2(const float2* __restrict__ FH,
                                             const float* __restrict__ Kr,
                                             float2* __restrict__ CONV,
                                             float* __restrict__ out) {
    __shared__ float2 SH[128 * 65];
    int bid = blockIdx.x;
    if (bid < 256) einsum_body(FH, Kr, CONV, SH, bid);
    else {
        int img = bid - 256;                    // 0..127 -> out0
        ifuse_body(FH + (size_t)img * 8192, (float2*)(out + (size_t)img * 16384), SH);
    }
}

__global__ __launch_bounds__(512) void ifuse1(const float2* __restrict__ CV,
                                              float* __restrict__ out1) {
    __shared__ float2 SH[128 * 65];
    int img = blockIdx.x;                       // 0..255 -> out1
    ifuse_body(CV + (size_t)img * 8192, (float2*)(out1 + (size_t)img * 16384), SH);
}

// ---------------------------------------------------------------------------
// Launch
// ---------------------------------------------------------------------------
extern "C" void kernel_launch(void* const* d_in, const int* in_sizes, int n_in,
                              void* d_out, int out_size, void* d_ws, size_t ws_size,
                              hipStream_t stream) {
    const float* f   = (const float*)d_in[0];   // (8,16,256,256)
    const float* kin = (const float*)d_in[1];   // (1,16,32,128,128)
    float* out = (float*)d_out;                 // (8,16,128,128) | (8,32,128,128)
    char* ws = (char*)d_ws;

    // workspace:
    //   [0, 16777216)         : G (128,256,64 c64) -> then CONV (256,128,64 c64)
    //   [16777216, 25165824)  : FHAT (128,128,64 c64)
    //   [33554432, 50331648)  : Kr (512,128,64 f32)
    float2* G    = (float2*)ws;
    float2* CONV = (float2*)ws;
    float2* FHAT = (float2*)(ws + 16777216);
    float*  Kr   = (float*)(ws + 33554432);

    rfft256<<<1024, 256, 0, stream>>>(f, G);                 // f rows
    mega1<<<1024, 512, 0, stream>>>(kin, Kr, G, FHAT);       // kfft (512) | fcol256 (512)
    mega2<<<384, 512, 0, stream>>>(FHAT, Kr, CONV, out);     // einsum (256) | ifuse out0 (128)
    ifuse1<<<256, 512, 0, stream>>>(CONV, out + 2097152);    // ifuse out1
}

// Round 8
// 159.645 us; speedup vs baseline: 2.8087x; 1.0315x over previous
//
#include <hip/hip_runtime.h>

#define PI_F 3.14159265358979f

typedef unsigned int  uint32;
typedef unsigned short ushort16;

// ---------------------------------------------------------------------------
// complex / bf16 helpers
// ---------------------------------------------------------------------------
__device__ __forceinline__ float2 cmul(float2 a, float2 b) {
    return make_float2(a.x * b.x - a.y * b.y, a.x * b.y + a.y * b.x);
}
__device__ __forceinline__ float2 cadd(float2 a, float2 b) { return make_float2(a.x + b.x, a.y + b.y); }
__device__ __forceinline__ float2 csub(float2 a, float2 b) { return make_float2(a.x - b.x, a.y - b.y); }
__device__ __forceinline__ float2 shflx(float2 v, int m) {
    return make_float2(__shfl_xor(v.x, m, 64), __shfl_xor(v.y, m, 64));
}
__device__ __forceinline__ float2 shfli(float2 v, int src) {
    return make_float2(__shfl(v.x, src, 64), __shfl(v.y, src, 64));
}
__device__ __forceinline__ int brev6(int x) { return (int)(__brev((unsigned)x) >> 26); }

__device__ __forceinline__ uint32 bfu(float x) {              // fp32 -> bf16 (RNE), low 16
    uint32 u = __float_as_uint(x);
    return (u + 0x7FFFu + ((u >> 16) & 1u)) >> 16;
}
__device__ __forceinline__ uint32 packbf2(float2 v) { return bfu(v.x) | (bfu(v.y) << 16); }
__device__ __forceinline__ float2 unpackbf2(uint32 u) {
    return make_float2(__uint_as_float(u << 16), __uint_as_float(u & 0xFFFF0000u));
}
__device__ __forceinline__ float bf2f(ushort16 u) { return __uint_as_float((uint32)u << 16); }

// DPP cross-lane exchange (no LDS pipe): xor1 = quad_perm[1,0,3,2] (0xB1),
// xor2 = quad_perm[2,3,0,1] (0x4E), xor8 = row_ror:8 (0x128).
template<int CTRL>
__device__ __forceinline__ float dpp1(float x) {
    return __builtin_bit_cast(float, __builtin_amdgcn_update_dpp(
        0, __builtin_bit_cast(int, x), CTRL, 0xF, 0xF, true));
}
template<int CTRL>
__device__ __forceinline__ float2 dppx(float2 v) {
    return make_float2(dpp1<CTRL>(v.x), dpp1<CTRL>(v.y));
}
template<int M>
__device__ __forceinline__ float2 xorx(float2 v) {
    if constexpr (M == 1)      return dppx<0xB1>(v);
    else if constexpr (M == 2) return dppx<0x4E>(v);
    else if constexpr (M == 8) return dppx<0x128>(v);
    else                       return shflx(v, M);
}

// Per-lane twiddles for the 6 shuffle DIF stages (m = 32,16,8,4,2,1).
template<bool INV>
__device__ __forceinline__ void tw_init(int lane, float2* w, float* sg) {
#pragma unroll
    for (int t = 0; t < 6; ++t) {
        int m = 32 >> t;
        bool up = (lane & m) != 0;
        int pos = lane & (m - 1);
        float ang = (INV ? PI_F : -PI_F) * (float)pos / (float)m;
        float sn, cs;
        __sincosf(ang, &sn, &cs);
        w[t]  = up ? make_float2(cs, sn) : make_float2(1.f, 0.f);
        sg[t] = up ? -1.f : 1.f;
    }
}

// 64-pt DIF FFT across the wave, 1 elem/lane. Natural in; out: lane l holds X[brev6(l)].
__device__ __forceinline__ float2 fft64s(float2 v, const float2* w, const float* sg) {
#define FFT_STAGE(T, M) { float2 p = xorx<M>(v);                                   \
        float2 d = make_float2(fmaf(sg[T], v.x, p.x), fmaf(sg[T], v.y, p.y));      \
        v = cmul(d, w[T]); }
    FFT_STAGE(0, 32) FFT_STAGE(1, 16) FFT_STAGE(2, 8)
    FFT_STAGE(3, 4)  FFT_STAGE(4, 2)  FFT_STAGE(5, 1)
#undef FFT_STAGE
    return v;
}

// ---------------------------------------------------------------------------
// kfft body (one block per (c1,c2) image): rfft2(128x128) in regs +
// frequency-domain D4 symmetrization -> real K (128 x 64) in bf16.
// ---------------------------------------------------------------------------
__device__ void kfft_body(const float* __restrict__ kin, ushort16* __restrict__ kout,
                          float2* X, int img) {
    int lane = threadIdx.x & 63, wv = threadIdx.x >> 6;   // 8 waves
    float2 w[6]; float sg[6];
    tw_init<false>(lane, w, sg);
    int b6 = brev6(lane);
    float sn, cs;
    __sincosf(-PI_F * (float)lane * (1.0f / 64.0f), &sn, &cs);
    float2 w64 = make_float2(cs, sn);           // col intra-stage twiddle (lane-based)
    __sincosf(-PI_F * (float)b6 * (1.0f / 64.0f), &sn, &cs);
    float2 wub = make_float2(cs, sn);           // rfft unpack twiddle at k = b6
    const float2* in2 = (const float2*)(kin + (size_t)img * 16384);
    int gm2 = brev6((64 - b6) & 63);            // lane holding Z[(64-b6)&63]
    // ---- row phase: 16 rows per wave, rfft128 via cfft64 in regs ----
#pragma unroll 2
    for (int rr = 0; rr < 16; ++rr) {
        int r = wv * 16 + rr;
        float2 z = in2[r * 64 + lane];
        z = fft64s(z, w, sg);                   // lane l holds Z[brev6(l)]
        float2 zm = shfli(z, gm2);
        float ar = z.x + zm.x, ai = z.y - zm.y;
        float br = z.x - zm.x, bi = z.y + zm.y;
        float p = wub.x * br - wub.y * bi, q = wub.x * bi + wub.y * br;
        X[r * 65 + b6] = make_float2(0.5f * (ar + q), 0.5f * (ai - p));
    }
    __syncthreads();
    // ---- col phase: 8 cols per wave, cfft128 (2 regs/lane) ----
    float2 c0[8], c1[8];
#pragma unroll
    for (int cc = 0; cc < 8; ++cc) {
        int k = wv * 8 + cc;
        c0[cc] = X[lane * 65 + k];
        c1[cc] = X[(lane + 64) * 65 + k];
    }
    __syncthreads();                            // all X reads done; reuse LDS as Rr
    float* Rr = (float*)X;
#pragma unroll
    for (int cc = 0; cc < 8; ++cc) {
        int k = wv * 8 + cc;
        float2 r0 = c0[cc], r1 = c1[cc];
        float2 t = r0;
        r0 = cadd(t, r1);
        r1 = cmul(csub(t, r1), w64);
        r0 = fft64s(r0, w, sg);
        r1 = fft64s(r1, w, sg);
        Rr[(2 * b6) * 65 + k]     = r0.x;
        Rr[(2 * b6 + 1) * 65 + k] = r1.x;
    }
    __syncthreads();
    // ---- frequency-domain D4 symmetrization (ushort4 bf16 stores) ----
    ushort4* ko4 = (ushort4*)(kout + (size_t)img * 8192);
    for (int i = threadIdx.x; i < 2048; i += 512) {
        int n = i >> 4, k4 = (i & 15) << 2;
        float op[4];
#pragma unroll
        for (int m = 0; m < 4; ++m) {
            int k = k4 + m;
            float t1 = Rr[n * 65 + k];
            float t2 = Rr[((128 - n) & 127) * 65 + k];
            float t3, t4;
            if (n < 64) {
                t3 = Rr[k * 65 + n];
                t4 = Rr[((128 - k) & 127) * 65 + n];
            } else {
                int c2 = 128 - n; if (c2 > 63) c2 = 63;   // n==64 unused downstream
                t3 = Rr[((128 - k) & 127) * 65 + c2];
                t4 = Rr[k * 65 + c2];
            }
            op[m] = 0.25f * (t1 + t2 + t3 + t4);
        }
        ushort4 o4;
        o4.x = (ushort16)bfu(op[0]); o4.y = (ushort16)bfu(op[1]);
        o4.z = (ushort16)bfu(op[2]); o4.w = (ushort16)bfu(op[3]);
        ko4[i] = o4;
    }
}

// ---------------------------------------------------------------------------
// rfft256 body: row rfft256 via cfft128 in regs, 8 rows/wave, bf16 output.
// Even lane l computes X[2m], X[2m+1] (m = brev6(l) < 32) - 2 shuffles/row.
// ---------------------------------------------------------------------------
__device__ void rfft_body(const float* __restrict__ f, uint32* __restrict__ G, int bid) {
    int lane = threadIdx.x & 63, wv = threadIdx.x >> 6;   // 8 waves
    int row0 = (bid * 8 + wv) * 8;
    float2 w[6]; float sg[6];
    tw_init<false>(lane, w, sg);
    int m = brev6(lane);
    float sn, cs;
    __sincosf(-PI_F * (float)lane * (1.0f / 64.0f), &sn, &cs);
    float2 w64 = make_float2(cs, sn);
    __sincosf(-PI_F * (float)(2 * m) * (1.0f / 128.0f), &sn, &cs);
    float2 wue = make_float2(cs, sn);           // unpack twiddle, k = 2m
    __sincosf(-PI_F * (float)(2 * m + 1) * (1.0f / 128.0f), &sn, &cs);
    float2 wuo = make_float2(cs, sn);           // unpack twiddle, k = 2m+1
    int src_e = brev6((64 - m) & 63);           // lane holding Z[2*(64-m)] in r0
    int src_o = brev6(63 - m);                  // lane holding Z[2*(63-m)+1] in r1
    bool active = (lane & 1) == 0;              // m < 32
#pragma unroll 2
    for (int rr = 0; rr < 8; ++rr) {
        size_t row = (size_t)(row0 + rr);
        const float2* x = (const float2*)(f + row * 256);
        float2 r0 = x[lane], r1 = x[lane + 64];
        float2 t = r0;
        r0 = cadd(t, r1);
        r1 = cmul(csub(t, r1), w64);
        r0 = fft64s(r0, w, sg);                 // r0[l] = Z[2*brev6(l)]
        r1 = fft64s(r1, w, sg);                 // r1[l] = Z[2*brev6(l)+1]
        float2 zme = shfli(r0, src_e);          // Z[128-2m]
        float2 zmo = shfli(r1, src_o);          // Z[128-(2m+1)]
        float ar = r0.x + zme.x, ai = r0.y - zme.y;
        float br = r0.x - zme.x, bi = r0.y + zme.y;
        float p = wue.x * br - wue.y * bi, q = wue.x * bi + wue.y * br;
        uint32 xe = packbf2(make_float2(0.5f * (ar + q), 0.5f * (ai - p)));
        ar = r1.x + zmo.x; ai = r1.y - zmo.y;
        br = r1.x - zmo.x; bi = r1.y + zmo.y;
        p = wuo.x * br - wuo.y * bi; q = wuo.x * bi + wuo.y * br;
        uint32 xo = packbf2(make_float2(0.5f * (ar + q), 0.5f * (ai - p)));
        if (active) ((uint2*)(G + row * 64))[m] = make_uint2(xe, xo);
    }
}

// ---------------------------------------------------------------------------
// L1: kfft (bid<512) || rfft256 (bid>=512)
// ---------------------------------------------------------------------------
__global__ __launch_bounds__(512) void mega_a(const float* __restrict__ kin,
                                              ushort16* __restrict__ Kr,
                                              const float* __restrict__ f,
                                              uint32* __restrict__ G) {
    __shared__ float2 SH[128 * 65];
    int bid = blockIdx.x;
    if (bid < 512) kfft_body(kin, Kr, SH, bid);
    else           rfft_body(f, G, bid - 512);
}

// ---------------------------------------------------------------------------
// L2: col cfft256 (4 regs/lane) on 16-col groups of bf16 G, truncate to
// signed 128-row set, scale 0.25 -> bf16 FHAT. LDS = packed bf16 (17.4 KB).
// ---------------------------------------------------------------------------
__global__ __launch_bounds__(512) void fcolk(const uint32* __restrict__ G,
                                             uint32* __restrict__ FH) {
    __shared__ uint32 S[256 * 17];
    int img = blockIdx.x >> 2, qg = blockIdx.x & 3;
    int lane = threadIdx.x & 63, wv = threadIdx.x >> 6;   // 8 waves
    float2 w[6]; float sg[6];
    tw_init<false>(lane, w, sg);
    float sn, cs;
    __sincosf(-PI_F * (float)lane * (1.0f / 64.0f), &sn, &cs);
    float2 w64 = make_float2(cs, sn);
    __sincosf(-PI_F * (float)lane * (1.0f / 128.0f), &sn, &cs);
    float2 w128a = make_float2(cs, sn);
    __sincosf(-PI_F * (float)(lane + 64) * (1.0f / 128.0f), &sn, &cs);
    float2 w128b = make_float2(cs, sn);
    const uint32* src = G + (size_t)img * 16384 + qg * 16;
    for (int i = threadIdx.x; i < 4096; i += 512) {
        int r = i >> 4, c = i & 15;
        S[r * 17 + c] = src[(size_t)r * 64 + c];
    }
    __syncthreads();
    float2 q0[2], q1[2], q2[2], q3[2];
#pragma unroll
    for (int cc = 0; cc < 2; ++cc) {
        int c = wv * 2 + cc;
        q0[cc] = unpackbf2(S[(lane)       * 17 + c]);
        q1[cc] = unpackbf2(S[(lane +  64) * 17 + c]);
        q2[cc] = unpackbf2(S[(lane + 128) * 17 + c]);
        q3[cc] = unpackbf2(S[(lane + 192) * 17 + c]);
    }
    __syncthreads();                            // reads done; reuse S for output staging
    int b6 = brev6(lane);
#pragma unroll
    for (int cc = 0; cc < 2; ++cc) {
        int c = wv * 2 + cc;
        float2 r0 = q0[cc], r1 = q1[cc], r2 = q2[cc], r3 = q3[cc], t;
        t = r0; r0 = cadd(t, r2); r2 = cmul(csub(t, r2), w128a);
        t = r1; r1 = cadd(t, r3); r3 = cmul(csub(t, r3), w128b);
        t = r0; r0 = cadd(t, r1); r1 = cmul(csub(t, r1), w64);
        t = r2; r2 = cadd(t, r3); r3 = cmul(csub(t, r3), w64);
        r0 = fft64s(r0, w, sg); r1 = fft64s(r1, w, sg);
        r2 = fft64s(r2, w, sg); r3 = fft64s(r3, w, sg);
        float2 vv[4] = { r0, r2, r1, r3 };      // n = 4*b6 + j (brev2 order)
#pragma unroll
        for (int j = 0; j < 4; ++j) {
            int n = 4 * b6 + j;
            int r = (n < 64) ? n : ((n >= 193) ? n - 128 : -1);
            if (r >= 0)
                S[r * 17 + c] = packbf2(make_float2(vv[j].x * 0.25f, vv[j].y * 0.25f));
        }
    }
    __syncthreads();
    uint32* dst = FH + (size_t)img * 8192 + qg * 16;
    for (int i = threadIdx.x; i < 2048; i += 512) {
        int r = i >> 4, c = i & 15;
        dst[(size_t)r * 64 + c] = (r == 64) ? 0u : S[r * 17 + c];
    }
}

// ---------------------------------------------------------------------------
// einsum body: C[b,d,nk] = sum_c F[b,c,nk] * K[c,d,nk] (K real bf16).
// One 32-nk group per block, 512 threads. F staged packed in LDS (16 KB).
// ---------------------------------------------------------------------------
__device__ void einsum_body(const uint32* __restrict__ F, const ushort16* __restrict__ K,
                            uint32* __restrict__ C, uint32* Ft, int bid) {
    int nk0 = bid * 32;
    int t = threadIdx.x;
    for (int i = t; i < 4096; i += 512) {
        int bc = i >> 5, nl = i & 31;
        Ft[i] = F[(size_t)bc * 8192 + nk0 + nl];
    }
    __syncthreads();
    int nl = t & 31, dg = t >> 5;               // dg 0..15
    int nk = nk0 + nl;
    float2 acc[2][8] = {};
#pragma unroll
    for (int c = 0; c < 16; ++c) {
        float2 fv[8];
#pragma unroll
        for (int b = 0; b < 8; ++b) fv[b] = unpackbf2(Ft[(b * 16 + c) * 32 + nl]);
#pragma unroll
        for (int j = 0; j < 2; ++j) {
            int d = j * 16 + dg;
            float kv = bf2f(K[(size_t)(c * 32 + d) * 8192 + nk]);
#pragma unroll
            for (int b = 0; b < 8; ++b) {
                acc[j][b].x = fmaf(fv[b].x, kv, acc[j][b].x);
                acc[j][b].y = fmaf(fv[b].y, kv, acc[j][b].y);
            }
        }
    }
#pragma unroll
    for (int j = 0; j < 2; ++j) {
        int d = j * 16 + dg;
#pragma unroll
        for (int b = 0; b < 8; ++b)
            C[(size_t)(b * 32 + d) * 8192 + nk] = packbf2(acc[j][b]);
    }
}

// ---------------------------------------------------------------------------
// ifuse body (one output image, bf16 input): col icfft128 in regs, row pack +
// icfft64 in regs -> 128x128 fp32 reals, scaled 1/8192.
// ---------------------------------------------------------------------------
__device__ void ifuse_body(const uint32* __restrict__ src, float2* __restrict__ dst,
                           float2* S) {
    int lane = threadIdx.x & 63, wv = threadIdx.x >> 6;   // 8 waves
    float2 w[6]; float sg[6];
    tw_init<true>(lane, w, sg);
    float sn, cs;
    __sincosf(PI_F * (float)lane * (1.0f / 64.0f), &sn, &cs);
    float2 w64 = make_float2(cs, sn);           // inverse intra-stage AND pack twiddle
    for (int i = threadIdx.x; i < 8192; i += 512) {
        int r = i >> 6, c = i & 63;
        S[r * 65 + c] = unpackbf2(src[i]);
    }
    __syncthreads();
    float2 c0[8], c1[8];
#pragma unroll
    for (int cc = 0; cc < 8; ++cc) {
        int k = wv * 8 + cc;
        c0[cc] = S[lane * 65 + k];
        c1[cc] = S[(lane + 64) * 65 + k];
    }
    __syncthreads();
    int b6 = brev6(lane);
#pragma unroll
    for (int cc = 0; cc < 8; ++cc) {
        int k = wv * 8 + cc;
        float2 r0 = c0[cc], r1 = c1[cc];
        float2 t = r0;
        r0 = cadd(t, r1);
        r1 = cmul(csub(t, r1), w64);
        r0 = fft64s(r0, w, sg);
        r1 = fft64s(r1, w, sg);
        S[(2 * b6) * 65 + k]     = r0;
        S[(2 * b6 + 1) * 65 + k] = r1;
    }
    __syncthreads();
    // ---- row phase: irfft128 via icfft64, 16 rows per wave ----
#pragma unroll 2
    for (int rr = 0; rr < 16; ++rr) {
        int m = wv * 16 + rr;
        float2 X = S[m * 65 + lane];
        float2 Xm = shfli(X, (64 - lane) & 63);
        if (lane == 0) Xm = make_float2(0.f, 0.f);   // X[64] == 0
        float er = 0.5f * (X.x + Xm.x), ei = 0.5f * (X.y - Xm.y);
        float br = 0.5f * (X.x - Xm.x), bi = 0.5f * (X.y + Xm.y);
        float orr = w64.x * br - w64.y * bi, oi = w64.x * bi + w64.y * br;
        float2 Z = make_float2(er - oi, ei + orr);
        Z = fft64s(Z, w, sg);                   // lane l holds z[brev6(l)]
        dst[m * 64 + b6] = make_float2(Z.x * (1.0f / 8192.0f), Z.y * (1.0f / 8192.0f));
    }
}

// ---------------------------------------------------------------------------
// L3: einsum (bid<256) || ifuse out0 (bid>=256);  L4: ifuse out1
// ---------------------------------------------------------------------------
__global__ __launch_bounds__(512) void mega2(const uint32* __restrict__ FH,
                                             const ushort16* __restrict__ Kr,
                                             uint32* __restrict__ CONV,
                                             float* __restrict__ out) {
    __shared__ float2 SH[128 * 65];
    int bid = blockIdx.x;
    if (bid < 256) einsum_body(FH, Kr, CONV, (uint32*)SH, bid);
    else {
        int img = bid - 256;                    // 0..127 -> out0
        ifuse_body(FH + (size_t)img * 8192, (float2*)(out + (size_t)img * 16384), SH);
    }
}

__global__ __launch_bounds__(512) void ifuse1(const uint32* __restrict__ CV,
                                              float* __restrict__ out1) {
    __shared__ float2 SH[128 * 65];
    int img = blockIdx.x;                       // 0..255 -> out1
    ifuse_body(CV + (size_t)img * 8192, (float2*)(out1 + (size_t)img * 16384), SH);
}

// ---------------------------------------------------------------------------
// Launch
// ---------------------------------------------------------------------------
extern "C" void kernel_launch(void* const* d_in, const int* in_sizes, int n_in,
                              void* d_out, int out_size, void* d_ws, size_t ws_size,
                              hipStream_t stream) {
    const float* f   = (const float*)d_in[0];   // (8,16,256,256)
    const float* kin = (const float*)d_in[1];   // (1,16,32,128,128)
    float* out = (float*)d_out;                 // (8,16,128,128) | (8,32,128,128)
    char* ws = (char*)d_ws;

    // workspace (bf16 intermediates):
    //   [0, 8388608)          : G (32768 x 64 bf16c) -> then CONV (256 x 8192 bf16c)
    //   [8388608, 12582912)   : FHAT (128 x 8192 bf16c)
    //   [16777216, 25165824)  : Kr (512 x 8192 bf16)
    uint32*   G    = (uint32*)ws;
    uint32*   CONV = (uint32*)ws;
    uint32*   FHAT = (uint32*)(ws + 8388608);
    ushort16* Kr   = (ushort16*)(ws + 16777216);

    mega_a<<<1024, 512, 0, stream>>>(kin, Kr, f, G);         // kfft || rfft256
    fcolk<<<512, 512, 0, stream>>>(G, FHAT);                 // col fft256 + truncate
    mega2<<<384, 512, 0, stream>>>(FHAT, Kr, CONV, out);     // einsum || ifuse out0
    ifuse1<<<256, 512, 0, stream>>>(CONV, out + 2097152);    // ifuse out1
}